// Round 12
// baseline (203.625 us; speedup 1.0000x reference)
//
#include <hip/hip_runtime.h>

#define NB   1024
#define SINQ 256
#define SPRQ 128
#define HIDQ 512

// pos_enc: emb[:, :3] = sin(pos * inv_freq[c]); inv_freq[c] = 10000^(-2c/256)
#define PEF1  0.93057207f
#define PEF2  0.86596438f
#define LOG2E 1.44269504089f
// q pre-scale: 1/sqrt(3) * log2(e)
#define QS    0.83298066476f

typedef _Float16 h2 __attribute__((ext_vector_type(2)));
typedef float    f2 __attribute__((ext_vector_type(2)));

#if defined(__has_builtin) && __has_builtin(__builtin_amdgcn_exp2f)
#define EXP2(x) __builtin_amdgcn_exp2f(x)
#else
#define EXP2(x) exp2f(x)
#endif

#if defined(__has_builtin) && __has_builtin(__builtin_amdgcn_fdot2)
#define FDOT2(a, b, c) __builtin_amdgcn_fdot2((a), (b), (c), false)
#else
__device__ __forceinline__ float fdot2_sw(h2 a, h2 b, float c) {
  return fmaf((float)a.x, (float)b.x, fmaf((float)a.y, (float)b.y, c));
}
#define FDOT2(a, b, c) fdot2_sw((a), (b), (c))
#endif

__device__ __forceinline__ unsigned pk16(float a, float b) {
  h2 v; v.x = (_Float16)a; v.y = (_Float16)b;
  return __builtin_bit_cast(unsigned, v);
}
__device__ __forceinline__ h2 uph(unsigned u) { return __builtin_bit_cast(h2, u); }

__device__ __forceinline__ h2 relu2(h2 z) {
#if defined(__has_builtin) && __has_builtin(__builtin_elementwise_max)
  h2 zz; zz.x = (_Float16)0.f; zz.y = (_Float16)0.f;
  return __builtin_elementwise_max(z, zz);
#else
  z.x = z.x > (_Float16)0.f ? z.x : (_Float16)0.f;
  z.y = z.y > (_Float16)0.f ? z.y : (_Float16)0.f;
  return z;
#endif
}

__device__ __forceinline__ f2 mkf2(float a, float b) { f2 r; r.x = a; r.y = b; return r; }
__device__ __forceinline__ f2 spl(float a) { f2 r; r.x = a; r.y = a; return r; }
#if defined(__has_builtin) && __has_builtin(__builtin_elementwise_fma)
__device__ __forceinline__ f2 fma2(f2 a, f2 b, f2 c) {
  return __builtin_elementwise_fma(a, b, c);   // v_pk_fma_f32
}
#else
__device__ __forceinline__ f2 fma2(f2 a, f2 b, f2 c) {
  f2 r; r.x = fmaf(a.x, b.x, c.x); r.y = fmaf(a.y, b.y, c.y); return r;
}
#endif

// ---- DPP quad_perm cross-lane --------------------------------------------
// PROVEN-SAFE on gfx950 (R6/R7/R9 passing): quad_perm 0xB1/0x4E (xor1/xor2),
// quad-broadcast 0x00/0x55/0xAA/0xFF, pair-swap 0x11.
// OFF-LIMITS: ROW_MIRROR/ROW_HALF_MIRROR (0x140/0x141) — removed on CDNA
// (R1 absmax-8.78 failure). Cross-quad strides stay __shfl_xor.
// SPILL LEDGER (R8): VGPR<=60 spill-free @256thr; 64 spilled. Load at use.
// RATE MODEL (R11 post-mortem): the dot2/cvt_pkrtz V-accumulation ISSUED
// MORE VALU than pk_fma_f32 (VALUBusy up, time up) — pk_fma f32 retained.
// R12: occupancy lever — 8-way slot split, 512 thr/block, 32 waves/CU.
#define DPPF(x, ctrl) __builtin_bit_cast(float, __builtin_amdgcn_update_dpp( \
    0, __builtin_bit_cast(int, (x)), (ctrl), 0xF, 0xF, true))
#define DPPU(x, ctrl) ((unsigned)__builtin_amdgcn_update_dpp( \
    0, (int)(x), (ctrl), 0xF, 0xF, true))

// xor-combine over the 8 slot lanes (quad DPP + cross-quad shfl).
#define C8S(v)  { (v) += DPPF((v), 0xB1); (v) += DPPF((v), 0x4E); \
                  (v) += __shfl_xor((v), 4, 64); }

// register-only selects (v_cndmask chains) -- NEVER index private arrays
// with a runtime value: that demotes them to scratch (HBM!).
__device__ __forceinline__ float sel4(float a, float b, float c, float d, int s) {
  float r = a;
  r = (s == 1) ? b : r;
  r = (s == 2) ? c : r;
  r = (s == 3) ? d : r;
  return r;
}
__device__ __forceinline__ float sel2(float a, float b, int s) {
  return s ? b : a;
}

// Block-wide (512 thr / 8 waves) mean/rstd over nelem values. One barrier
// per call (rotated sRed slots). Strides 1,2 via quad_perm DPP; 4..32 shfl.
__device__ __forceinline__ void block_stats(float s1, float s2, float* slot,
                                            int tid, float nelem,
                                            float& mean, float& rstd) {
  s1 += DPPF(s1, 0xB1); s2 += DPPF(s2, 0xB1);
  s1 += DPPF(s1, 0x4E); s2 += DPPF(s2, 0x4E);
#pragma unroll
  for (int off = 32; off >= 4; off >>= 1) {
    s1 += __shfl_xor(s1, off, 64);
    s2 += __shfl_xor(s2, off, 64);
  }
  if ((tid & 63) == 0) {
    slot[((tid >> 6) << 1) + 0] = s1;
    slot[((tid >> 6) << 1) + 1] = s2;
  }
  __syncthreads();
  float t1 = 0.f, t2 = 0.f;
#pragma unroll
  for (int w = 0; w < 8; ++w) { t1 += slot[2 * w]; t2 += slot[2 * w + 1]; }
  mean = t1 / nelem;
  rstd = rsqrtf(t2 / nelem - mean * mean + 1e-5f);
}

// One 512-thr block per batch element (R12: 8-way slot split s=t&7, halving
// per-thread loop work and doubling resident waves 16->32/CU). Queries and
// LN rows duplicate across the two half-groups (exact 2x sums, nelem 1536).
// pack_tabs folded (R5); quad-T LDS (R4/R11); DPP quad ops (R6); queries
// built once per row (R7); pk_fma f32 accumulation (R9, dot2 reverted).
__global__ __launch_bounds__(512, 8) void fused_fwd(
    const float* __restrict__ X, const float* __restrict__ T,
    const float* __restrict__ einw, const float* __restrict__ einb,
    const float* __restrict__ eow,  const float* __restrict__ eob,
    const float* __restrict__ eln1w, const float* __restrict__ eln1b,
    const float* __restrict__ eb2,
    const float* __restrict__ eln2w, const float* __restrict__ eln2b,
    const float* __restrict__ a1w, const float* __restrict__ a1b,
    const float* __restrict__ a1ow, const float* __restrict__ a1ob,
    const float* __restrict__ dln1w, const float* __restrict__ dln1b,
    const float* __restrict__ a2w, const float* __restrict__ a2b,
    const float* __restrict__ a2ow, const float* __restrict__ a2ob,
    const float* __restrict__ db2,
    const float* __restrict__ dln3w, const float* __restrict__ dln3b,
    const float* __restrict__ ew1, const float* __restrict__ eb1,
    const float* __restrict__ ew2,
    const float* __restrict__ dw1, const float* __restrict__ db1,
    const float* __restrict__ dw2,
    float* __restrict__ out)
{
  __shared__ uint4  sFE[2 * 256];                       // 8 KB enc FFN
  __shared__ uint4  sFD[2 * 256];                       // 8 KB dec FFN
  __shared__ __align__(16) float sEPq[(SINQ / 4) * 12]; // 3 KB p_X quad-T
  __shared__ __align__(16) float sDPq[(SPRQ / 4) * 12]; // 1.5 KB p_T quad-T
  __shared__ __align__(16) float sCEq[(SINQ / 4) * 12]; // 3 KB enc_out quad-T
  __shared__ float  sRed[5 * 16];                       // per-call slots

  const int b = blockIdx.x;
  const int t = threadIdx.x;
  const int s = t & 7;             // slot (0..7)
  const int g = t >> 3;            // row-group (0..63)

  // ---- staging split: t<256 stage enc rows; t>=256 pack tables;
  //      t>=384 additionally stage dec rows.
  if (t < 256) {
    const float p = (float)t;
    const float pe0 = __sinf(p), pe1 = __sinf(p * PEF1), pe2 = __sinf(p * PEF2);
    const float* xr = X + (size_t)b * SINQ * 3 + 3 * t;
    const float p0 = xr[0] + pe0, p1 = xr[1] + pe1, p2 = xr[2] + pe2;
    const int q = t >> 2, sl = t & 3;
    sEPq[(q * 3 + 0) * 4 + sl] = p0;
    sEPq[(q * 3 + 1) * 4 + sl] = p1;
    sEPq[(q * 3 + 2) * 4 + sl] = p2;
  } else {
    const int tt = t - 256;        // 0..255 table pair index
    const float2 e10 = *(const float2*)&ew1[6 * tt];
    const float2 e11 = *(const float2*)&ew1[6 * tt + 2];
    const float2 e12 = *(const float2*)&ew1[6 * tt + 4];
    const float2 eb  = *(const float2*)&eb1[2 * tt];
    sFE[2 * tt] = make_uint4(pk16(e10.x, e11.y), pk16(e10.y, e12.x),
                             pk16(e11.x, e12.y), pk16(eb.x, eb.y));
    const float2 w20 = *(const float2*)&ew2[2 * tt];
    const float2 w21 = *(const float2*)&ew2[HIDQ + 2 * tt];
    const float2 w22 = *(const float2*)&ew2[2 * HIDQ + 2 * tt];
    sFE[2 * tt + 1] = make_uint4(pk16(w20.x, w20.y), pk16(w21.x, w21.y),
                                 pk16(w22.x, w22.y), 0u);
    const float2 d10 = *(const float2*)&dw1[6 * tt];
    const float2 d11 = *(const float2*)&dw1[6 * tt + 2];
    const float2 d12 = *(const float2*)&dw1[6 * tt + 4];
    const float2 dbv = *(const float2*)&db1[2 * tt];
    sFD[2 * tt] = make_uint4(pk16(d10.x, d11.y), pk16(d10.y, d12.x),
                             pk16(d11.x, d12.y), pk16(dbv.x, dbv.y));
    const float2 v20 = *(const float2*)&dw2[2 * tt];
    const float2 v21 = *(const float2*)&dw2[HIDQ + 2 * tt];
    const float2 v22 = *(const float2*)&dw2[2 * HIDQ + 2 * tt];
    sFD[2 * tt + 1] = make_uint4(pk16(v20.x, v20.y), pk16(v21.x, v21.y),
                                 pk16(v22.x, v22.y), 0u);
    if (t >= 384) {
      const int r = t - 384;       // dec row 0..127
      const float p = (float)r;
      const float pe0 = __sinf(p), pe1 = __sinf(p * PEF1), pe2 = __sinf(p * PEF2);
      const float* tr = T + (size_t)b * SPRQ * 3 + 3 * r;
      const float d0 = tr[0] + pe0, d1 = tr[1] + pe1, d2 = tr[2] + pe2;
      const int q = r >> 2, sl = r & 3;
      sDPq[(q * 3 + 0) * 4 + sl] = d0;
      sDPq[(q * 3 + 1) * 4 + sl] = d1;
      sDPq[(q * 3 + 2) * 4 + sl] = d2;
    }
  }
  __syncthreads();

  const f2 z2 = mkf2(0.f, 0.f);
  float r0, r1, r2;
  float mean, rstd;

  // ================= ENCODER =================
  const int s4 = s & 3;
  const int rho = g + 64 * s4;     // own enc row (duplicated on s and s+4)
  float pr0, pr1, pr2;
  {
    const int qo = rho >> 2, so = rho & 3;
    pr0 = sEPq[(qo * 3 + 0) * 4 + so];
    pr1 = sEPq[(qo * 3 + 1) * 4 + so];
    pr2 = sEPq[(qo * 3 + 2) * 4 + so];
  }

  // build ONLY own row's query, then quad-broadcast (R7)
  f2 qaO, qbO;
  {
    const float q0 = (einw[0] * pr0 + einw[1] * pr1 + einw[2] * pr2 + einb[0]) * QS;
    const float q1 = (einw[3] * pr0 + einw[4] * pr1 + einw[5] * pr2 + einb[1]) * QS;
    const float q2 = (einw[6] * pr0 + einw[7] * pr1 + einw[8] * pr2 + einb[2]) * QS;
    qaO = mkf2(q0 * einw[9]  + q1 * einw[12] + q2 * einw[15],
               q0 * einw[10] + q1 * einw[13] + q2 * einw[16]);
    qbO = mkf2(q0 * einw[11] + q1 * einw[14] + q2 * einw[17],
               q0 * einb[3]  + q1 * einb[4]  + q2 * einb[5]);
  }
  f2 qxs[4], qys[4], qzs[4], qcs[4];
  qxs[0] = spl(DPPF(qaO.x, 0x00)); qxs[1] = spl(DPPF(qaO.x, 0x55));
  qxs[2] = spl(DPPF(qaO.x, 0xAA)); qxs[3] = spl(DPPF(qaO.x, 0xFF));
  qys[0] = spl(DPPF(qaO.y, 0x00)); qys[1] = spl(DPPF(qaO.y, 0x55));
  qys[2] = spl(DPPF(qaO.y, 0xAA)); qys[3] = spl(DPPF(qaO.y, 0xFF));
  qzs[0] = spl(DPPF(qbO.x, 0x00)); qzs[1] = spl(DPPF(qbO.x, 0x55));
  qzs[2] = spl(DPPF(qbO.x, 0xAA)); qzs[3] = spl(DPPF(qbO.x, 0xFF));
  qcs[0] = spl(DPPF(qbO.y, 0x00)); qcs[1] = spl(DPPF(qbO.y, 0x55));
  qcs[2] = spl(DPPF(qbO.y, 0xAA)); qcs[3] = spl(DPPF(qbO.y, 0xFF));

  // attention: slot s handles key-quads qid = 8*u+s (8 key-quads/thread)
  f2 a0p[4], a1p[4], a2p[4], dnp[4];
#pragma unroll
  for (int m = 0; m < 4; ++m) { a0p[m] = z2; a1p[m] = z2; a2p[m] = z2; dnp[m] = z2; }
#pragma unroll 2
  for (int u = 0; u < 8; ++u) {
    const int qid = 8 * u + s;
    const float4 P0 = *(const float4*)&sEPq[(qid * 3 + 0) * 4];
    const float4 P1 = *(const float4*)&sEPq[(qid * 3 + 1) * 4];
    const float4 P2 = *(const float4*)&sEPq[(qid * 3 + 2) * 4];
    const f2 p0l = mkf2(P0.x, P0.y), p0h = mkf2(P0.z, P0.w);
    const f2 p1l = mkf2(P1.x, P1.y), p1h = mkf2(P1.z, P1.w);
    const f2 p2l = mkf2(P2.x, P2.y), p2h = mkf2(P2.z, P2.w);
#pragma unroll
    for (int m = 0; m < 4; ++m) {
      const f2 sl = fma2(p0l, qxs[m], fma2(p1l, qys[m], fma2(p2l, qzs[m], qcs[m])));
      const f2 sh = fma2(p0h, qxs[m], fma2(p1h, qys[m], fma2(p2h, qzs[m], qcs[m])));
      const f2 el = mkf2(EXP2(sl.x), EXP2(sl.y));
      const f2 eh = mkf2(EXP2(sh.x), EXP2(sh.y));
      dnp[m] = dnp[m] + el + eh;
      a0p[m] = fma2(el, p0l, fma2(eh, p0h, a0p[m]));
      a1p[m] = fma2(el, p1l, fma2(eh, p1h, a1p[m]));
      a2p[m] = fma2(el, p2l, fma2(eh, p2h, a2p[m]));
    }
  }
  float aa0[4], aa1[4], aa2[4], adn[4];
#pragma unroll
  for (int m = 0; m < 4; ++m) {
    aa0[m] = a0p[m].x + a0p[m].y; C8S(aa0[m]);
    aa1[m] = a1p[m].x + a1p[m].y; C8S(aa1[m]);
    aa2[m] = a2p[m].x + a2p[m].y; C8S(aa2[m]);
    adn[m] = dnp[m].x + dnp[m].y; C8S(adn[m]);
  }

  {
    const float myd  = sel4(adn[0], adn[1], adn[2], adn[3], s4);
    const float mya0 = sel4(aa0[0], aa0[1], aa0[2], aa0[3], s4);
    const float mya1 = sel4(aa1[0], aa1[1], aa1[2], aa1[3], s4);
    const float mya2 = sel4(aa2[0], aa2[1], aa2[2], aa2[3], s4);
    const float rdn = 1.f / myd;
    const float u0 = mya0 * rdn, u1 = mya1 * rdn, u2 = mya2 * rdn;
    const float v0 = einw[18] * u0 + einw[19] * u1 + einw[20] * u2 + einb[6];
    const float v1 = einw[21] * u0 + einw[22] * u1 + einw[23] * u2 + einb[7];
    const float v2 = einw[24] * u0 + einw[25] * u1 + einw[26] * u2 + einb[8];
    r0 = eow[0] * v0 + eow[1] * v1 + eow[2] * v2 + eob[0] + pr0;
    r1 = eow[3] * v0 + eow[4] * v1 + eow[5] * v2 + eob[1] + pr1;
    r2 = eow[6] * v0 + eow[7] * v1 + eow[8] * v2 + eob[2] + pr2;
  }
  // each row contributed by 2 threads (s and s+4) -> nelem = 2*768
  block_stats(r0 + r1 + r2, r0 * r0 + r1 * r1 + r2 * r2, sRed + 0, t, 1536.f, mean, rstd);
  const int lie = rho * 3;
  const float x20 = (r0 - mean) * rstd * eln1w[lie + 0] + eln1b[lie + 0];
  const float x21 = (r1 - mean) * rstd * eln1w[lie + 1] + eln1b[lie + 1];
  const float x22 = (r2 - mean) * rstd * eln1w[lie + 2] + eln1b[lie + 2];

  // FFN: slot s handles pairs pp = 8*jj+s over 4 quad-gathered rows (DPP bcast)
  unsigned xxm[4], xym[4], xzm[4];
  {
    const unsigned xx = pk16(x20, x20), xy = pk16(x21, x21), xz = pk16(x22, x22);
    xxm[0] = DPPU(xx, 0x00); xym[0] = DPPU(xy, 0x00); xzm[0] = DPPU(xz, 0x00);
    xxm[1] = DPPU(xx, 0x55); xym[1] = DPPU(xy, 0x55); xzm[1] = DPPU(xz, 0x55);
    xxm[2] = DPPU(xx, 0xAA); xym[2] = DPPU(xy, 0xAA); xzm[2] = DPPU(xz, 0xAA);
    xxm[3] = DPPU(xx, 0xFF); xym[3] = DPPU(xy, 0xFF); xzm[3] = DPPU(xz, 0xFF);
  }
  float c0[4] = {0, 0, 0, 0}, c1[4] = {0, 0, 0, 0}, c2[4] = {0, 0, 0, 0};
#pragma unroll 4
  for (int jj = 0; jj < 32; ++jj) {
    const int pp = 8 * jj + s;
    const uint4 A = sFE[2 * pp];
    const uint4 B = sFE[2 * pp + 1];
    const h2 w1x = uph(A.x), w1y = uph(A.y), w1z = uph(A.z), b1h = uph(A.w);
    const h2 w2x = uph(B.x), w2y = uph(B.y), w2z = uph(B.z);
#pragma unroll
    for (int m = 0; m < 4; ++m) {
      h2 z = w1z * uph(xzm[m]) + b1h;
      z = w1y * uph(xym[m]) + z;
      z = w1x * uph(xxm[m]) + z;
      z = relu2(z);
      c0[m] = FDOT2(z, w2x, c0[m]);
      c1[m] = FDOT2(z, w2y, c1[m]);
      c2[m] = FDOT2(z, w2z, c2[m]);
    }
  }
#pragma unroll
  for (int m = 0; m < 4; ++m) { C8S(c0[m]); C8S(c1[m]); C8S(c2[m]); }

  const float h0 = sel4(c0[0], c0[1], c0[2], c0[3], s4) + eb2[0] + x20;
  const float h1 = sel4(c1[0], c1[1], c1[2], c1[3], s4) + eb2[1] + x21;
  const float h2v = sel4(c2[0], c2[1], c2[2], c2[3], s4) + eb2[2] + x22;
  block_stats(h0 + h1 + h2v, h0 * h0 + h1 * h1 + h2v * h2v, sRed + 16, t, 1536.f, mean, rstd);
  if (s < 4) {                      // one writer per enc row
    const float e0 = (h0 - mean) * rstd * eln2w[lie + 0] + eln2b[lie + 0];
    const float e1 = (h1 - mean) * rstd * eln2w[lie + 1] + eln2b[lie + 1];
    const float e2 = (h2v - mean) * rstd * eln2w[lie + 2] + eln2b[lie + 2];
    const int q = rho >> 2, sl = rho & 3;
    sCEq[(q * 3 + 0) * 4 + sl] = e0;
    sCEq[(q * 3 + 1) * 4 + sl] = e1;
    sCEq[(q * 3 + 2) * 4 + sl] = e2;
  }
  // no __syncthreads here (R9) — the dec-self block_stats barrier below
  // orders all sCEq writes before any cross-attn read.

  // ================= DECODER =================
  const int ms = s & 1;            // assigned row: ra = g + 64*ms
  const int ra = g + 64 * ms;

  float pt0, pt1, pt2;
  {
    const int qo = ra >> 2, so = ra & 3;
    pt0 = sDPq[(qo * 3 + 0) * 4 + so];
    pt1 = sDPq[(qo * 3 + 1) * 4 + so];
    pt2 = sDPq[(qo * 3 + 2) * 4 + so];
  }

  // own row's self-attn query; other row via pair-swap 0x11 (R7)
  f2 dqaO, dqbO;
  {
    const float q0 = (a1w[0] * pt0 + a1w[1] * pt1 + a1w[2] * pt2 + a1b[0]) * QS;
    const float q1 = (a1w[3] * pt0 + a1w[4] * pt1 + a1w[5] * pt2 + a1b[1]) * QS;
    const float q2 = (a1w[6] * pt0 + a1w[7] * pt1 + a1w[8] * pt2 + a1b[2]) * QS;
    dqaO = mkf2(q0 * a1w[9]  + q1 * a1w[12] + q2 * a1w[15],
                q0 * a1w[10] + q1 * a1w[13] + q2 * a1w[16]);
    dqbO = mkf2(q0 * a1w[11] + q1 * a1w[14] + q2 * a1w[17],
                q0 * a1b[3]  + q1 * a1b[4]  + q2 * a1b[5]);
  }
  f2 dqxs[2], dqys[2], dqzs[2];
  float ds0[2], dsE[2];            // seed and seed+LOG2E precomputed
  {
    const float oax = DPPF(dqaO.x, 0x11), oay = DPPF(dqaO.y, 0x11);
    const float obx = DPPF(dqbO.x, 0x11), oby = DPPF(dqbO.y, 0x11);
    dqxs[0] = spl(ms ? oax : dqaO.x); dqxs[1] = spl(ms ? dqaO.x : oax);
    dqys[0] = spl(ms ? oay : dqaO.y); dqys[1] = spl(ms ? dqaO.y : oay);
    dqzs[0] = spl(ms ? obx : dqbO.x); dqzs[1] = spl(ms ? dqbO.x : obx);
    ds0[0] = ms ? oby : dqbO.y;       ds0[1] = ms ? dqbO.y : oby;
    dsE[0] = ds0[0] + LOG2E;          dsE[1] = ds0[1] + LOG2E;
  }

  // self-attn (additive tril(ones) mask -> seed = ds0/dsE by j<=row)
  f2 d0p[2], d1p[2], d2p[2], ddp[2];
#pragma unroll
  for (int m = 0; m < 2; ++m) { d0p[m] = z2; d1p[m] = z2; d2p[m] = z2; ddp[m] = z2; }
#pragma unroll 2
  for (int u = 0; u < 4; ++u) {
    const int qid = 8 * u + s;
    const int j0 = 4 * qid;
    const float4 P0 = *(const float4*)&sDPq[(qid * 3 + 0) * 4];
    const float4 P1 = *(const float4*)&sDPq[(qid * 3 + 1) * 4];
    const float4 P2 = *(const float4*)&sDPq[(qid * 3 + 2) * 4];
    const f2 p0l = mkf2(P0.x, P0.y), p0h = mkf2(P0.z, P0.w);
    const f2 p1l = mkf2(P1.x, P1.y), p1h = mkf2(P1.z, P1.w);
    const f2 p2l = mkf2(P2.x, P2.y), p2h = mkf2(P2.z, P2.w);
#pragma unroll
    for (int m = 0; m < 2; ++m) {
      const int row = g + 64 * m;
      const f2 seedl = mkf2(j0 + 0 <= row ? dsE[m] : ds0[m],
                            j0 + 1 <= row ? dsE[m] : ds0[m]);
      const f2 seedh = mkf2(j0 + 2 <= row ? dsE[m] : ds0[m],
                            j0 + 3 <= row ? dsE[m] : ds0[m]);
      const f2 sl = fma2(p0l, dqxs[m], fma2(p1l, dqys[m], fma2(p2l, dqzs[m], seedl)));
      const f2 sh = fma2(p0h, dqxs[m], fma2(p1h, dqys[m], fma2(p2h, dqzs[m], seedh)));
      const f2 el = mkf2(EXP2(sl.x), EXP2(sl.y));
      const f2 eh = mkf2(EXP2(sh.x), EXP2(sh.y));
      ddp[m] = ddp[m] + el + eh;
      d0p[m] = fma2(el, p0l, fma2(eh, p0h, d0p[m]));
      d1p[m] = fma2(el, p1l, fma2(eh, p1h, d1p[m]));
      d2p[m] = fma2(el, p2l, fma2(eh, p2h, d2p[m]));
    }
  }
  float da0[2], da1[2], da2[2], ddn[2];
#pragma unroll
  for (int m = 0; m < 2; ++m) {
    da0[m] = d0p[m].x + d0p[m].y; C8S(da0[m]);
    da1[m] = d1p[m].x + d1p[m].y; C8S(da1[m]);
    da2[m] = d2p[m].x + d2p[m].y; C8S(da2[m]);
    ddn[m] = ddp[m].x + ddp[m].y; C8S(ddn[m]);
  }
  {
    const float myd = sel2(ddn[0], ddn[1], ms);
    const float rdn = 1.f / myd;
    const float u0 = sel2(da0[0], da0[1], ms) * rdn;
    const float u1 = sel2(da1[0], da1[1], ms) * rdn;
    const float u2 = sel2(da2[0], da2[1], ms) * rdn;
    const float v0 = a1w[18] * u0 + a1w[19] * u1 + a1w[20] * u2 + a1b[6];
    const float v1 = a1w[21] * u0 + a1w[22] * u1 + a1w[23] * u2 + a1b[7];
    const float v2 = a1w[24] * u0 + a1w[25] * u1 + a1w[26] * u2 + a1b[8];
    r0 = a1ow[0] * v0 + a1ow[1] * v1 + a1ow[2] * v2 + a1ob[0] + pt0;
    r1 = a1ow[3] * v0 + a1ow[4] * v1 + a1ow[5] * v2 + a1ob[1] + pt1;
    r2 = a1ow[6] * v0 + a1ow[7] * v1 + a1ow[8] * v2 + a1ob[2] + pt2;
  }
  const int contrib = (s < 2) ? 1 : 0;   // one contributor per dec row
  float mean2, rstd2;
  block_stats(contrib ? r0 + r1 + r2 : 0.f,
              contrib ? r0 * r0 + r1 * r1 + r2 * r2 : 0.f, sRed + 32, t, 384.f, mean2, rstd2);
  const int lid = ra * 3;
  const float dl1w0 = dln1w[lid + 0], dl1w1 = dln1w[lid + 1], dl1w2 = dln1w[lid + 2];
  const float dl1b0 = dln1b[lid + 0], dl1b1 = dln1b[lid + 1], dl1b2 = dln1b[lid + 2];
  const float x2d0 = (r0 - mean2) * rstd2 * dl1w0 + dl1b0;
  const float x2d1 = (r1 - mean2) * rstd2 * dl1w1 + dl1b1;
  const float x2d2 = (r2 - mean2) * rstd2 * dl1w2 + dl1b2;

  // cross-attn query built from OWN row's x2d; other row via 0x11 swap (R7)
  f2 cqaO, cqbO;
  {
    const float q0 = (a2w[0] * x2d0 + a2w[1] * x2d1 + a2w[2] * x2d2 + a2b[0]) * QS;
    const float q1 = (a2w[3] * x2d0 + a2w[4] * x2d1 + a2w[5] * x2d2 + a2b[1]) * QS;
    const float q2 = (a2w[6] * x2d0 + a2w[7] * x2d1 + a2w[8] * x2d2 + a2b[2]) * QS;
    cqaO = mkf2(q0 * a2w[9]  + q1 * a2w[12] + q2 * a2w[15],
                q0 * a2w[10] + q1 * a2w[13] + q2 * a2w[16]);
    cqbO = mkf2(q0 * a2w[11] + q1 * a2w[14] + q2 * a2w[17],
                q0 * a2b[3]  + q1 * a2b[4]  + q2 * a2b[5]);
  }
  f2 cqxs[2], cqys[2], cqzs[2], cqcs[2];
  {
    const float oax = DPPF(cqaO.x, 0x11), oay = DPPF(cqaO.y, 0x11);
    const float obx = DPPF(cqbO.x, 0x11), oby = DPPF(cqbO.y, 0x11);
    cqxs[0] = spl(ms ? oax : cqaO.x); cqxs[1] = spl(ms ? cqaO.x : oax);
    cqys[0] = spl(ms ? oay : cqaO.y); cqys[1] = spl(ms ? cqaO.y : oay);
    cqzs[0] = spl(ms ? obx : cqbO.x); cqzs[1] = spl(ms ? cqbO.x : obx);
    cqcs[0] = spl(ms ? oby : cqbO.y); cqcs[1] = spl(ms ? cqbO.y : oby);
  }
#pragma unroll
  for (int m = 0; m < 2; ++m) { d0p[m] = z2; d1p[m] = z2; d2p[m] = z2; ddp[m] = z2; }
#pragma unroll 2
  for (int u = 0; u < 8; ++u) {
    const int qid = 8 * u + s;
    const float4 P0 = *(const float4*)&sCEq[(qid * 3 + 0) * 4];
    const float4 P1 = *(const float4*)&sCEq[(qid * 3 + 1) * 4];
    const float4 P2 = *(const float4*)&sCEq[(qid * 3 + 2) * 4];
    const f2 p0l = mkf2(P0.x, P0.y), p0h = mkf2(P0.z, P0.w);
    const f2 p1l = mkf2(P1.x, P1.y), p1h = mkf2(P1.z, P1.w);
    const f2 p2l = mkf2(P2.x, P2.y), p2h = mkf2(P2.z, P2.w);
#pragma unroll
    for (int m = 0; m < 2; ++m) {
      const f2 sl = fma2(p0l, cqxs[m], fma2(p1l, cqys[m], fma2(p2l, cqzs[m], cqcs[m])));
      const f2 sh = fma2(p0h, cqxs[m], fma2(p1h, cqys[m], fma2(p2h, cqzs[m], cqcs[m])));
      const f2 el = mkf2(EXP2(sl.x), EXP2(sl.y));
      const f2 eh = mkf2(EXP2(sh.x), EXP2(sh.y));
      ddp[m] = ddp[m] + el + eh;
      d0p[m] = fma2(el, p0l, fma2(eh, p0h, d0p[m]));
      d1p[m] = fma2(el, p1l, fma2(eh, p1h, d1p[m]));
      d2p[m] = fma2(el, p2l, fma2(eh, p2h, d2p[m]));
    }
  }
#pragma unroll
  for (int m = 0; m < 2; ++m) {
    da0[m] = d0p[m].x + d0p[m].y; C8S(da0[m]);
    da1[m] = d1p[m].x + d1p[m].y; C8S(da1[m]);
    da2[m] = d2p[m].x + d2p[m].y; C8S(da2[m]);
    ddn[m] = ddp[m].x + ddp[m].y; C8S(ddn[m]);
  }
  {
    const float myd = sel2(ddn[0], ddn[1], ms);
    const float rdn = 1.f / myd;
    const float u0 = sel2(da0[0], da0[1], ms) * rdn;
    const float u1 = sel2(da1[0], da1[1], ms) * rdn;
    const float u2 = sel2(da2[0], da2[1], ms) * rdn;
    const float v0 = a2w[18] * u0 + a2w[19] * u1 + a2w[20] * u2 + a2b[6];
    const float v1 = a2w[21] * u0 + a2w[22] * u1 + a2w[23] * u2 + a2b[7];
    const float v2 = a2w[24] * u0 + a2w[25] * u1 + a2w[26] * u2 + a2b[8];
    r0 = a2ow[0] * v0 + a2ow[1] * v1 + a2ow[2] * v2 + a2ob[0] + x2d0;
    r1 = a2ow[3] * v0 + a2ow[4] * v1 + a2ow[5] * v2 + a2ob[1] + x2d1;
    r2 = a2ow[6] * v0 + a2ow[7] * v1 + a2ow[8] * v2 + a2ob[2] + x2d2;
  }
  block_stats(contrib ? r0 + r1 + r2 : 0.f,
              contrib ? r0 * r0 + r1 * r1 + r2 * r2 : 0.f, sRed + 48, t, 384.f, mean2, rstd2);
  const float x30 = (r0 - mean2) * rstd2 * dl1w0 + dl1b0;   // dec_ln1 AGAIN
  const float x31 = (r1 - mean2) * rstd2 * dl1w1 + dl1b1;
  const float x32 = (r2 - mean2) * rstd2 * dl1w2 + dl1b2;

  // dec FFN: both rows' x3 as h2 broadcasts (DPP pair-swap + selects)
  unsigned x3x0, x3y0, x3z0, x3x1, x3y1, x3z1;
  {
    const unsigned xx = pk16(x30, x30), xy = pk16(x31, x31), xz = pk16(x32, x32);
    const unsigned oxx = DPPU(xx, 0x11);
    const unsigned oxy = DPPU(xy, 0x11);
    const unsigned oxz = DPPU(xz, 0x11);
    x3x0 = ms ? oxx : xx; x3y0 = ms ? oxy : xy; x3z0 = ms ? oxz : xz;
    x3x1 = ms ? xx : oxx; x3y1 = ms ? xy : oxy; x3z1 = ms ? xz : oxz;
  }
  float e0[2] = {0, 0}, e1[2] = {0, 0}, e2[2] = {0, 0};
#pragma unroll 4
  for (int jj = 0; jj < 32; ++jj) {
    const int pp = 8 * jj + s;
    const uint4 A = sFD[2 * pp];
    const uint4 B = sFD[2 * pp + 1];
    const h2 w1x = uph(A.x), w1y = uph(A.y), w1z = uph(A.z), b1h = uph(A.w);
    const h2 w2x = uph(B.x), w2y = uph(B.y), w2z = uph(B.z);
#pragma unroll
    for (int m = 0; m < 2; ++m) {
      h2 z = w1z * uph(m ? x3z1 : x3z0) + b1h;
      z = w1y * uph(m ? x3y1 : x3y0) + z;
      z = w1x * uph(m ? x3x1 : x3x0) + z;
      z = relu2(z);
      e0[m] = FDOT2(z, w2x, e0[m]);
      e1[m] = FDOT2(z, w2y, e1[m]);
      e2[m] = FDOT2(z, w2z, e2[m]);
    }
  }
#pragma unroll
  for (int m = 0; m < 2; ++m) { C8S(e0[m]); C8S(e1[m]); C8S(e2[m]); }

  const float f0 = sel2(e0[0], e0[1], ms) + db2[0] + x30;
  const float f1 = sel2(e1[0], e1[1], ms) + db2[1] + x31;
  const float f2v = sel2(e2[0], e2[1], ms) + db2[2] + x32;
  block_stats(contrib ? f0 + f1 + f2v : 0.f,
              contrib ? f0 * f0 + f1 * f1 + f2v * f2v : 0.f, sRed + 64, t, 384.f, mean2, rstd2);
  if (s < 2) {
    float* op = out + ((size_t)b * SPRQ + ra) * 3;
    op[0] = (f0 - mean2) * rstd2 * dln3w[lid + 0] + dln3b[lid + 0];
    op[1] = (f1 - mean2) * rstd2 * dln3w[lid + 1] + dln3b[lid + 1];
    op[2] = (f2v - mean2) * rstd2 * dln3w[lid + 2] + dln3b[lid + 2];
  }
}

extern "C" void kernel_launch(void* const* d_in, const int* in_sizes, int n_in,
                              void* d_out, int out_size, void* d_ws, size_t ws_size,
                              hipStream_t stream) {
  (void)in_sizes; (void)n_in; (void)out_size; (void)d_ws; (void)ws_size;

  fused_fwd<<<NB, 512, 0, stream>>>(
      (const float*)d_in[0],  (const float*)d_in[1],
      (const float*)d_in[2],  (const float*)d_in[3],
      (const float*)d_in[4],  (const float*)d_in[5],
      (const float*)d_in[6],  (const float*)d_in[7],
      (const float*)d_in[11],
      (const float*)d_in[12], (const float*)d_in[13],
      (const float*)d_in[14], (const float*)d_in[15],
      (const float*)d_in[16], (const float*)d_in[17],
      (const float*)d_in[18], (const float*)d_in[19],
      (const float*)d_in[20], (const float*)d_in[21],
      (const float*)d_in[22], (const float*)d_in[23],
      (const float*)d_in[27],
      (const float*)d_in[28], (const float*)d_in[29],
      (const float*)d_in[8],  (const float*)d_in[9],  (const float*)d_in[10],
      (const float*)d_in[24], (const float*)d_in[25], (const float*)d_in[26],
      (float*)d_out);
}

// Round 13
// 174.602 us; speedup vs baseline: 1.1662x; 1.1662x over previous
//
#include <hip/hip_runtime.h>

#define NB   1024
#define SINQ 256
#define SPRQ 128
#define HIDQ 512

// pos_enc: emb[:, :3] = sin(pos * inv_freq[c]); inv_freq[c] = 10000^(-2c/256)
#define PEF1  0.93057207f
#define PEF2  0.86596438f
#define LOG2E 1.44269504089f
// q pre-scale: 1/sqrt(3) * log2(e)
#define QS    0.83298066476f

typedef _Float16 h2 __attribute__((ext_vector_type(2)));
typedef float    f2 __attribute__((ext_vector_type(2)));

#if defined(__has_builtin) && __has_builtin(__builtin_amdgcn_exp2f)
#define EXP2(x) __builtin_amdgcn_exp2f(x)
#else
#define EXP2(x) exp2f(x)
#endif

#if defined(__has_builtin) && __has_builtin(__builtin_amdgcn_fdot2)
#define FDOT2(a, b, c) __builtin_amdgcn_fdot2((a), (b), (c), false)
#else
__device__ __forceinline__ float fdot2_sw(h2 a, h2 b, float c) {
  return fmaf((float)a.x, (float)b.x, fmaf((float)a.y, (float)b.y, c));
}
#define FDOT2(a, b, c) fdot2_sw((a), (b), (c))
#endif

__device__ __forceinline__ unsigned pk16(float a, float b) {
  h2 v; v.x = (_Float16)a; v.y = (_Float16)b;
  return __builtin_bit_cast(unsigned, v);
}
__device__ __forceinline__ h2 uph(unsigned u) { return __builtin_bit_cast(h2, u); }

__device__ __forceinline__ h2 relu2(h2 z) {
#if defined(__has_builtin) && __has_builtin(__builtin_elementwise_max)
  h2 zz; zz.x = (_Float16)0.f; zz.y = (_Float16)0.f;
  return __builtin_elementwise_max(z, zz);
#else
  z.x = z.x > (_Float16)0.f ? z.x : (_Float16)0.f;
  z.y = z.y > (_Float16)0.f ? z.y : (_Float16)0.f;
  return z;
#endif
}

__device__ __forceinline__ f2 mkf2(float a, float b) { f2 r; r.x = a; r.y = b; return r; }
__device__ __forceinline__ f2 spl(float a) { f2 r; r.x = a; r.y = a; return r; }
#if defined(__has_builtin) && __has_builtin(__builtin_elementwise_fma)
__device__ __forceinline__ f2 fma2(f2 a, f2 b, f2 c) {
  return __builtin_elementwise_fma(a, b, c);   // v_pk_fma_f32
}
#else
__device__ __forceinline__ f2 fma2(f2 a, f2 b, f2 c) {
  f2 r; r.x = fmaf(a.x, b.x, c.x); r.y = fmaf(a.y, b.y, c.y); return r;
}
#endif

// ---- DPP quad_perm cross-lane --------------------------------------------
// PROVEN-SAFE on gfx950 (R6/R7/R9 passing): quad_perm 0xB1/0x4E (xor1/xor2),
// quad-broadcast 0x00/0x55/0xAA/0xFF, pair-swap 0x11.
// OFF-LIMITS: ROW_MIRROR/ROW_HALF_MIRROR (0x140/0x141) — removed on CDNA.
// SPILL LEDGER (R8/R12): body needs ~55-60 VGPR. @256thr launch_bounds(,4)
// cap 128 = safe; R12's (512,8) cap 64 -> VGPR 32 + 113 MB scratch, 103 us.
// R13: (512,6) cap ~85 -> fits, 24 waves/CU (vs 16). Tripwire: WRITE_SIZE.
// RATE MODEL (R11): dot2/cvt_pkrtz V-accum issued MORE VALU than pk_fma f32.
#define DPPF(x, ctrl) __builtin_bit_cast(float, __builtin_amdgcn_update_dpp( \
    0, __builtin_bit_cast(int, (x)), (ctrl), 0xF, 0xF, true))
#define DPPU(x, ctrl) ((unsigned)__builtin_amdgcn_update_dpp( \
    0, (int)(x), (ctrl), 0xF, 0xF, true))

// xor-combine over the 8 slot lanes (quad DPP + cross-quad shfl).
#define C8S(v)  { (v) += DPPF((v), 0xB1); (v) += DPPF((v), 0x4E); \
                  (v) += __shfl_xor((v), 4, 64); }

// register-only selects (v_cndmask chains) -- NEVER index private arrays
// with a runtime value: that demotes them to scratch (HBM!).
__device__ __forceinline__ float sel4(float a, float b, float c, float d, int s) {
  float r = a;
  r = (s == 1) ? b : r;
  r = (s == 2) ? c : r;
  r = (s == 3) ? d : r;
  return r;
}
__device__ __forceinline__ float sel2(float a, float b, int s) {
  return s ? b : a;
}

// Block-wide (512 thr / 8 waves) mean/rstd over nelem values. One barrier
// per call (rotated sRed slots). Strides 1,2 via quad_perm DPP; 4..32 shfl.
__device__ __forceinline__ void block_stats(float s1, float s2, float* slot,
                                            int tid, float nelem,
                                            float& mean, float& rstd) {
  s1 += DPPF(s1, 0xB1); s2 += DPPF(s2, 0xB1);
  s1 += DPPF(s1, 0x4E); s2 += DPPF(s2, 0x4E);
#pragma unroll
  for (int off = 32; off >= 4; off >>= 1) {
    s1 += __shfl_xor(s1, off, 64);
    s2 += __shfl_xor(s2, off, 64);
  }
  if ((tid & 63) == 0) {
    slot[((tid >> 6) << 1) + 0] = s1;
    slot[((tid >> 6) << 1) + 1] = s2;
  }
  __syncthreads();
  float t1 = 0.f, t2 = 0.f;
#pragma unroll
  for (int w = 0; w < 8; ++w) { t1 += slot[2 * w]; t2 += slot[2 * w + 1]; }
  mean = t1 / nelem;
  rstd = rsqrtf(t2 / nelem - mean * mean + 1e-5f);
}

// One 512-thr block per batch element (8-way slot split s=t&7; R12 logic,
// proven correct). R13: launch_bounds (512,6) -> VGPR cap ~85, no spill,
// 3 blocks/CU = 24 waves/CU. Queries/LN rows duplicate across half-groups
// (exact 2x sums, nelem 1536). pack_tabs folded (R5); quad-T LDS (R4/R11);
// DPP quad ops (R6); queries built once per row (R7); pk_fma f32 (R9).
__global__ __launch_bounds__(512, 6) void fused_fwd(
    const float* __restrict__ X, const float* __restrict__ T,
    const float* __restrict__ einw, const float* __restrict__ einb,
    const float* __restrict__ eow,  const float* __restrict__ eob,
    const float* __restrict__ eln1w, const float* __restrict__ eln1b,
    const float* __restrict__ eb2,
    const float* __restrict__ eln2w, const float* __restrict__ eln2b,
    const float* __restrict__ a1w, const float* __restrict__ a1b,
    const float* __restrict__ a1ow, const float* __restrict__ a1ob,
    const float* __restrict__ dln1w, const float* __restrict__ dln1b,
    const float* __restrict__ a2w, const float* __restrict__ a2b,
    const float* __restrict__ a2ow, const float* __restrict__ a2ob,
    const float* __restrict__ db2,
    const float* __restrict__ dln3w, const float* __restrict__ dln3b,
    const float* __restrict__ ew1, const float* __restrict__ eb1,
    const float* __restrict__ ew2,
    const float* __restrict__ dw1, const float* __restrict__ db1,
    const float* __restrict__ dw2,
    float* __restrict__ out)
{
  __shared__ uint4  sFE[2 * 256];                       // 8 KB enc FFN
  __shared__ uint4  sFD[2 * 256];                       // 8 KB dec FFN
  __shared__ __align__(16) float sEPq[(SINQ / 4) * 12]; // 3 KB p_X quad-T
  __shared__ __align__(16) float sDPq[(SPRQ / 4) * 12]; // 1.5 KB p_T quad-T
  __shared__ __align__(16) float sCEq[(SINQ / 4) * 12]; // 3 KB enc_out quad-T
  __shared__ float  sRed[5 * 16];                       // per-call slots

  const int b = blockIdx.x;
  const int t = threadIdx.x;
  const int s = t & 7;             // slot (0..7)
  const int g = t >> 3;            // row-group (0..63)

  // ---- staging split: t<256 stage enc rows; t>=256 pack tables;
  //      t>=384 additionally stage dec rows.
  if (t < 256) {
    const float p = (float)t;
    const float pe0 = __sinf(p), pe1 = __sinf(p * PEF1), pe2 = __sinf(p * PEF2);
    const float* xr = X + (size_t)b * SINQ * 3 + 3 * t;
    const float p0 = xr[0] + pe0, p1 = xr[1] + pe1, p2 = xr[2] + pe2;
    const int q = t >> 2, sl = t & 3;
    sEPq[(q * 3 + 0) * 4 + sl] = p0;
    sEPq[(q * 3 + 1) * 4 + sl] = p1;
    sEPq[(q * 3 + 2) * 4 + sl] = p2;
  } else {
    const int tt = t - 256;        // 0..255 table pair index
    const float2 e10 = *(const float2*)&ew1[6 * tt];
    const float2 e11 = *(const float2*)&ew1[6 * tt + 2];
    const float2 e12 = *(const float2*)&ew1[6 * tt + 4];
    const float2 eb  = *(const float2*)&eb1[2 * tt];
    sFE[2 * tt] = make_uint4(pk16(e10.x, e11.y), pk16(e10.y, e12.x),
                             pk16(e11.x, e12.y), pk16(eb.x, eb.y));
    const float2 w20 = *(const float2*)&ew2[2 * tt];
    const float2 w21 = *(const float2*)&ew2[HIDQ + 2 * tt];
    const float2 w22 = *(const float2*)&ew2[2 * HIDQ + 2 * tt];
    sFE[2 * tt + 1] = make_uint4(pk16(w20.x, w20.y), pk16(w21.x, w21.y),
                                 pk16(w22.x, w22.y), 0u);
    const float2 d10 = *(const float2*)&dw1[6 * tt];
    const float2 d11 = *(const float2*)&dw1[6 * tt + 2];
    const float2 d12 = *(const float2*)&dw1[6 * tt + 4];
    const float2 dbv = *(const float2*)&db1[2 * tt];
    sFD[2 * tt] = make_uint4(pk16(d10.x, d11.y), pk16(d10.y, d12.x),
                             pk16(d11.x, d12.y), pk16(dbv.x, dbv.y));
    const float2 v20 = *(const float2*)&dw2[2 * tt];
    const float2 v21 = *(const float2*)&dw2[HIDQ + 2 * tt];
    const float2 v22 = *(const float2*)&dw2[2 * HIDQ + 2 * tt];
    sFD[2 * tt + 1] = make_uint4(pk16(v20.x, v20.y), pk16(v21.x, v21.y),
                                 pk16(v22.x, v22.y), 0u);
    if (t >= 384) {
      const int r = t - 384;       // dec row 0..127
      const float p = (float)r;
      const float pe0 = __sinf(p), pe1 = __sinf(p * PEF1), pe2 = __sinf(p * PEF2);
      const float* tr = T + (size_t)b * SPRQ * 3 + 3 * r;
      const float d0 = tr[0] + pe0, d1 = tr[1] + pe1, d2 = tr[2] + pe2;
      const int q = r >> 2, sl = r & 3;
      sDPq[(q * 3 + 0) * 4 + sl] = d0;
      sDPq[(q * 3 + 1) * 4 + sl] = d1;
      sDPq[(q * 3 + 2) * 4 + sl] = d2;
    }
  }
  __syncthreads();

  const f2 z2 = mkf2(0.f, 0.f);
  float r0, r1, r2;
  float mean, rstd;

  // ================= ENCODER =================
  const int s4 = s & 3;
  const int rho = g + 64 * s4;     // own enc row (duplicated on s and s+4)
  float pr0, pr1, pr2;
  {
    const int qo = rho >> 2, so = rho & 3;
    pr0 = sEPq[(qo * 3 + 0) * 4 + so];
    pr1 = sEPq[(qo * 3 + 1) * 4 + so];
    pr2 = sEPq[(qo * 3 + 2) * 4 + so];
  }

  // build ONLY own row's query, then quad-broadcast (R7)
  f2 qaO, qbO;
  {
    const float q0 = (einw[0] * pr0 + einw[1] * pr1 + einw[2] * pr2 + einb[0]) * QS;
    const float q1 = (einw[3] * pr0 + einw[4] * pr1 + einw[5] * pr2 + einb[1]) * QS;
    const float q2 = (einw[6] * pr0 + einw[7] * pr1 + einw[8] * pr2 + einb[2]) * QS;
    qaO = mkf2(q0 * einw[9]  + q1 * einw[12] + q2 * einw[15],
               q0 * einw[10] + q1 * einw[13] + q2 * einw[16]);
    qbO = mkf2(q0 * einw[11] + q1 * einw[14] + q2 * einw[17],
               q0 * einb[3]  + q1 * einb[4]  + q2 * einb[5]);
  }
  f2 qxs[4], qys[4], qzs[4], qcs[4];
  qxs[0] = spl(DPPF(qaO.x, 0x00)); qxs[1] = spl(DPPF(qaO.x, 0x55));
  qxs[2] = spl(DPPF(qaO.x, 0xAA)); qxs[3] = spl(DPPF(qaO.x, 0xFF));
  qys[0] = spl(DPPF(qaO.y, 0x00)); qys[1] = spl(DPPF(qaO.y, 0x55));
  qys[2] = spl(DPPF(qaO.y, 0xAA)); qys[3] = spl(DPPF(qaO.y, 0xFF));
  qzs[0] = spl(DPPF(qbO.x, 0x00)); qzs[1] = spl(DPPF(qbO.x, 0x55));
  qzs[2] = spl(DPPF(qbO.x, 0xAA)); qzs[3] = spl(DPPF(qbO.x, 0xFF));
  qcs[0] = spl(DPPF(qbO.y, 0x00)); qcs[1] = spl(DPPF(qbO.y, 0x55));
  qcs[2] = spl(DPPF(qbO.y, 0xAA)); qcs[3] = spl(DPPF(qbO.y, 0xFF));

  // attention: slot s handles key-quads qid = 8*u+s (8 key-quads/thread)
  f2 a0p[4], a1p[4], a2p[4], dnp[4];
#pragma unroll
  for (int m = 0; m < 4; ++m) { a0p[m] = z2; a1p[m] = z2; a2p[m] = z2; dnp[m] = z2; }
#pragma unroll 2
  for (int u = 0; u < 8; ++u) {
    const int qid = 8 * u + s;
    const float4 P0 = *(const float4*)&sEPq[(qid * 3 + 0) * 4];
    const float4 P1 = *(const float4*)&sEPq[(qid * 3 + 1) * 4];
    const float4 P2 = *(const float4*)&sEPq[(qid * 3 + 2) * 4];
    const f2 p0l = mkf2(P0.x, P0.y), p0h = mkf2(P0.z, P0.w);
    const f2 p1l = mkf2(P1.x, P1.y), p1h = mkf2(P1.z, P1.w);
    const f2 p2l = mkf2(P2.x, P2.y), p2h = mkf2(P2.z, P2.w);
#pragma unroll
    for (int m = 0; m < 4; ++m) {
      const f2 sl = fma2(p0l, qxs[m], fma2(p1l, qys[m], fma2(p2l, qzs[m], qcs[m])));
      const f2 sh = fma2(p0h, qxs[m], fma2(p1h, qys[m], fma2(p2h, qzs[m], qcs[m])));
      const f2 el = mkf2(EXP2(sl.x), EXP2(sl.y));
      const f2 eh = mkf2(EXP2(sh.x), EXP2(sh.y));
      dnp[m] = dnp[m] + el + eh;
      a0p[m] = fma2(el, p0l, fma2(eh, p0h, a0p[m]));
      a1p[m] = fma2(el, p1l, fma2(eh, p1h, a1p[m]));
      a2p[m] = fma2(el, p2l, fma2(eh, p2h, a2p[m]));
    }
  }
  float aa0[4], aa1[4], aa2[4], adn[4];
#pragma unroll
  for (int m = 0; m < 4; ++m) {
    aa0[m] = a0p[m].x + a0p[m].y; C8S(aa0[m]);
    aa1[m] = a1p[m].x + a1p[m].y; C8S(aa1[m]);
    aa2[m] = a2p[m].x + a2p[m].y; C8S(aa2[m]);
    adn[m] = dnp[m].x + dnp[m].y; C8S(adn[m]);
  }

  {
    const float myd  = sel4(adn[0], adn[1], adn[2], adn[3], s4);
    const float mya0 = sel4(aa0[0], aa0[1], aa0[2], aa0[3], s4);
    const float mya1 = sel4(aa1[0], aa1[1], aa1[2], aa1[3], s4);
    const float mya2 = sel4(aa2[0], aa2[1], aa2[2], aa2[3], s4);
    const float rdn = 1.f / myd;
    const float u0 = mya0 * rdn, u1 = mya1 * rdn, u2 = mya2 * rdn;
    const float v0 = einw[18] * u0 + einw[19] * u1 + einw[20] * u2 + einb[6];
    const float v1 = einw[21] * u0 + einw[22] * u1 + einw[23] * u2 + einb[7];
    const float v2 = einw[24] * u0 + einw[25] * u1 + einw[26] * u2 + einb[8];
    r0 = eow[0] * v0 + eow[1] * v1 + eow[2] * v2 + eob[0] + pr0;
    r1 = eow[3] * v0 + eow[4] * v1 + eow[5] * v2 + eob[1] + pr1;
    r2 = eow[6] * v0 + eow[7] * v1 + eow[8] * v2 + eob[2] + pr2;
  }
  // each row contributed by 2 threads (s and s+4) -> nelem = 2*768
  block_stats(r0 + r1 + r2, r0 * r0 + r1 * r1 + r2 * r2, sRed + 0, t, 1536.f, mean, rstd);
  const int lie = rho * 3;
  const float x20 = (r0 - mean) * rstd * eln1w[lie + 0] + eln1b[lie + 0];
  const float x21 = (r1 - mean) * rstd * eln1w[lie + 1] + eln1b[lie + 1];
  const float x22 = (r2 - mean) * rstd * eln1w[lie + 2] + eln1b[lie + 2];

  // FFN: slot s handles pairs pp = 8*jj+s over 4 quad-gathered rows (DPP bcast)
  unsigned xxm[4], xym[4], xzm[4];
  {
    const unsigned xx = pk16(x20, x20), xy = pk16(x21, x21), xz = pk16(x22, x22);
    xxm[0] = DPPU(xx, 0x00); xym[0] = DPPU(xy, 0x00); xzm[0] = DPPU(xz, 0x00);
    xxm[1] = DPPU(xx, 0x55); xym[1] = DPPU(xy, 0x55); xzm[1] = DPPU(xz, 0x55);
    xxm[2] = DPPU(xx, 0xAA); xym[2] = DPPU(xy, 0xAA); xzm[2] = DPPU(xz, 0xAA);
    xxm[3] = DPPU(xx, 0xFF); xym[3] = DPPU(xy, 0xFF); xzm[3] = DPPU(xz, 0xFF);
  }
  float c0[4] = {0, 0, 0, 0}, c1[4] = {0, 0, 0, 0}, c2[4] = {0, 0, 0, 0};
#pragma unroll 4
  for (int jj = 0; jj < 32; ++jj) {
    const int pp = 8 * jj + s;
    const uint4 A = sFE[2 * pp];
    const uint4 B = sFE[2 * pp + 1];
    const h2 w1x = uph(A.x), w1y = uph(A.y), w1z = uph(A.z), b1h = uph(A.w);
    const h2 w2x = uph(B.x), w2y = uph(B.y), w2z = uph(B.z);
#pragma unroll
    for (int m = 0; m < 4; ++m) {
      h2 z = w1z * uph(xzm[m]) + b1h;
      z = w1y * uph(xym[m]) + z;
      z = w1x * uph(xxm[m]) + z;
      z = relu2(z);
      c0[m] = FDOT2(z, w2x, c0[m]);
      c1[m] = FDOT2(z, w2y, c1[m]);
      c2[m] = FDOT2(z, w2z, c2[m]);
    }
  }
#pragma unroll
  for (int m = 0; m < 4; ++m) { C8S(c0[m]); C8S(c1[m]); C8S(c2[m]); }

  const float h0 = sel4(c0[0], c0[1], c0[2], c0[3], s4) + eb2[0] + x20;
  const float h1 = sel4(c1[0], c1[1], c1[2], c1[3], s4) + eb2[1] + x21;
  const float h2v = sel4(c2[0], c2[1], c2[2], c2[3], s4) + eb2[2] + x22;
  block_stats(h0 + h1 + h2v, h0 * h0 + h1 * h1 + h2v * h2v, sRed + 16, t, 1536.f, mean, rstd);
  if (s < 4) {                      // one writer per enc row
    const float e0 = (h0 - mean) * rstd * eln2w[lie + 0] + eln2b[lie + 0];
    const float e1 = (h1 - mean) * rstd * eln2w[lie + 1] + eln2b[lie + 1];
    const float e2 = (h2v - mean) * rstd * eln2w[lie + 2] + eln2b[lie + 2];
    const int q = rho >> 2, sl = rho & 3;
    sCEq[(q * 3 + 0) * 4 + sl] = e0;
    sCEq[(q * 3 + 1) * 4 + sl] = e1;
    sCEq[(q * 3 + 2) * 4 + sl] = e2;
  }
  // no __syncthreads here (R9) — the dec-self block_stats barrier below
  // orders all sCEq writes before any cross-attn read.

  // ================= DECODER =================
  const int ms = s & 1;            // assigned row: ra = g + 64*ms
  const int ra = g + 64 * ms;

  float pt0, pt1, pt2;
  {
    const int qo = ra >> 2, so = ra & 3;
    pt0 = sDPq[(qo * 3 + 0) * 4 + so];
    pt1 = sDPq[(qo * 3 + 1) * 4 + so];
    pt2 = sDPq[(qo * 3 + 2) * 4 + so];
  }

  // own row's self-attn query; other row via pair-swap 0x11 (R7)
  f2 dqaO, dqbO;
  {
    const float q0 = (a1w[0] * pt0 + a1w[1] * pt1 + a1w[2] * pt2 + a1b[0]) * QS;
    const float q1 = (a1w[3] * pt0 + a1w[4] * pt1 + a1w[5] * pt2 + a1b[1]) * QS;
    const float q2 = (a1w[6] * pt0 + a1w[7] * pt1 + a1w[8] * pt2 + a1b[2]) * QS;
    dqaO = mkf2(q0 * a1w[9]  + q1 * a1w[12] + q2 * a1w[15],
                q0 * a1w[10] + q1 * a1w[13] + q2 * a1w[16]);
    dqbO = mkf2(q0 * a1w[11] + q1 * a1w[14] + q2 * a1w[17],
                q0 * a1b[3]  + q1 * a1b[4]  + q2 * a1b[5]);
  }
  f2 dqxs[2], dqys[2], dqzs[2];
  float ds0[2], dsE[2];            // seed and seed+LOG2E precomputed
  {
    const float oax = DPPF(dqaO.x, 0x11), oay = DPPF(dqaO.y, 0x11);
    const float obx = DPPF(dqbO.x, 0x11), oby = DPPF(dqbO.y, 0x11);
    dqxs[0] = spl(ms ? oax : dqaO.x); dqxs[1] = spl(ms ? dqaO.x : oax);
    dqys[0] = spl(ms ? oay : dqaO.y); dqys[1] = spl(ms ? dqaO.y : oay);
    dqzs[0] = spl(ms ? obx : dqbO.x); dqzs[1] = spl(ms ? dqbO.x : obx);
    ds0[0] = ms ? oby : dqbO.y;       ds0[1] = ms ? dqbO.y : oby;
    dsE[0] = ds0[0] + LOG2E;          dsE[1] = ds0[1] + LOG2E;
  }

  // self-attn (additive tril(ones) mask -> seed = ds0/dsE by j<=row)
  f2 d0p[2], d1p[2], d2p[2], ddp[2];
#pragma unroll
  for (int m = 0; m < 2; ++m) { d0p[m] = z2; d1p[m] = z2; d2p[m] = z2; ddp[m] = z2; }
#pragma unroll 2
  for (int u = 0; u < 4; ++u) {
    const int qid = 8 * u + s;
    const int j0 = 4 * qid;
    const float4 P0 = *(const float4*)&sDPq[(qid * 3 + 0) * 4];
    const float4 P1 = *(const float4*)&sDPq[(qid * 3 + 1) * 4];
    const float4 P2 = *(const float4*)&sDPq[(qid * 3 + 2) * 4];
    const f2 p0l = mkf2(P0.x, P0.y), p0h = mkf2(P0.z, P0.w);
    const f2 p1l = mkf2(P1.x, P1.y), p1h = mkf2(P1.z, P1.w);
    const f2 p2l = mkf2(P2.x, P2.y), p2h = mkf2(P2.z, P2.w);
#pragma unroll
    for (int m = 0; m < 2; ++m) {
      const int row = g + 64 * m;
      const f2 seedl = mkf2(j0 + 0 <= row ? dsE[m] : ds0[m],
                            j0 + 1 <= row ? dsE[m] : ds0[m]);
      const f2 seedh = mkf2(j0 + 2 <= row ? dsE[m] : ds0[m],
                            j0 + 3 <= row ? dsE[m] : ds0[m]);
      const f2 sl = fma2(p0l, dqxs[m], fma2(p1l, dqys[m], fma2(p2l, dqzs[m], seedl)));
      const f2 sh = fma2(p0h, dqxs[m], fma2(p1h, dqys[m], fma2(p2h, dqzs[m], seedh)));
      const f2 el = mkf2(EXP2(sl.x), EXP2(sl.y));
      const f2 eh = mkf2(EXP2(sh.x), EXP2(sh.y));
      ddp[m] = ddp[m] + el + eh;
      d0p[m] = fma2(el, p0l, fma2(eh, p0h, d0p[m]));
      d1p[m] = fma2(el, p1l, fma2(eh, p1h, d1p[m]));
      d2p[m] = fma2(el, p2l, fma2(eh, p2h, d2p[m]));
    }
  }
  float da0[2], da1[2], da2[2], ddn[2];
#pragma unroll
  for (int m = 0; m < 2; ++m) {
    da0[m] = d0p[m].x + d0p[m].y; C8S(da0[m]);
    da1[m] = d1p[m].x + d1p[m].y; C8S(da1[m]);
    da2[m] = d2p[m].x + d2p[m].y; C8S(da2[m]);
    ddn[m] = ddp[m].x + ddp[m].y; C8S(ddn[m]);
  }
  {
    const float myd = sel2(ddn[0], ddn[1], ms);
    const float rdn = 1.f / myd;
    const float u0 = sel2(da0[0], da0[1], ms) * rdn;
    const float u1 = sel2(da1[0], da1[1], ms) * rdn;
    const float u2 = sel2(da2[0], da2[1], ms) * rdn;
    const float v0 = a1w[18] * u0 + a1w[19] * u1 + a1w[20] * u2 + a1b[6];
    const float v1 = a1w[21] * u0 + a1w[22] * u1 + a1w[23] * u2 + a1b[7];
    const float v2 = a1w[24] * u0 + a1w[25] * u1 + a1w[26] * u2 + a1b[8];
    r0 = a1ow[0] * v0 + a1ow[1] * v1 + a1ow[2] * v2 + a1ob[0] + pt0;
    r1 = a1ow[3] * v0 + a1ow[4] * v1 + a1ow[5] * v2 + a1ob[1] + pt1;
    r2 = a1ow[6] * v0 + a1ow[7] * v1 + a1ow[8] * v2 + a1ob[2] + pt2;
  }
  const int contrib = (s < 2) ? 1 : 0;   // one contributor per dec row
  float mean2, rstd2;
  block_stats(contrib ? r0 + r1 + r2 : 0.f,
              contrib ? r0 * r0 + r1 * r1 + r2 * r2 : 0.f, sRed + 32, t, 384.f, mean2, rstd2);
  const int lid = ra * 3;
  const float dl1w0 = dln1w[lid + 0], dl1w1 = dln1w[lid + 1], dl1w2 = dln1w[lid + 2];
  const float dl1b0 = dln1b[lid + 0], dl1b1 = dln1b[lid + 1], dl1b2 = dln1b[lid + 2];
  const float x2d0 = (r0 - mean2) * rstd2 * dl1w0 + dl1b0;
  const float x2d1 = (r1 - mean2) * rstd2 * dl1w1 + dl1b1;
  const float x2d2 = (r2 - mean2) * rstd2 * dl1w2 + dl1b2;

  // cross-attn query built from OWN row's x2d; other row via 0x11 swap (R7)
  f2 cqaO, cqbO;
  {
    const float q0 = (a2w[0] * x2d0 + a2w[1] * x2d1 + a2w[2] * x2d2 + a2b[0]) * QS;
    const float q1 = (a2w[3] * x2d0 + a2w[4] * x2d1 + a2w[5] * x2d2 + a2b[1]) * QS;
    const float q2 = (a2w[6] * x2d0 + a2w[7] * x2d1 + a2w[8] * x2d2 + a2b[2]) * QS;
    cqaO = mkf2(q0 * a2w[9]  + q1 * a2w[12] + q2 * a2w[15],
                q0 * a2w[10] + q1 * a2w[13] + q2 * a2w[16]);
    cqbO = mkf2(q0 * a2w[11] + q1 * a2w[14] + q2 * a2w[17],
                q0 * a2b[3]  + q1 * a2b[4]  + q2 * a2b[5]);
  }
  f2 cqxs[2], cqys[2], cqzs[2], cqcs[2];
  {
    const float oax = DPPF(cqaO.x, 0x11), oay = DPPF(cqaO.y, 0x11);
    const float obx = DPPF(cqbO.x, 0x11), oby = DPPF(cqbO.y, 0x11);
    cqxs[0] = spl(ms ? oax : cqaO.x); cqxs[1] = spl(ms ? cqaO.x : oax);
    cqys[0] = spl(ms ? oay : cqaO.y); cqys[1] = spl(ms ? cqaO.y : oay);
    cqzs[0] = spl(ms ? obx : cqbO.x); cqzs[1] = spl(ms ? cqbO.x : obx);
    cqcs[0] = spl(ms ? oby : cqbO.y); cqcs[1] = spl(ms ? cqbO.y : oby);
  }
#pragma unroll
  for (int m = 0; m < 2; ++m) { d0p[m] = z2; d1p[m] = z2; d2p[m] = z2; ddp[m] = z2; }
#pragma unroll 2
  for (int u = 0; u < 8; ++u) {
    const int qid = 8 * u + s;
    const float4 P0 = *(const float4*)&sCEq[(qid * 3 + 0) * 4];
    const float4 P1 = *(const float4*)&sCEq[(qid * 3 + 1) * 4];
    const float4 P2 = *(const float4*)&sCEq[(qid * 3 + 2) * 4];
    const f2 p0l = mkf2(P0.x, P0.y), p0h = mkf2(P0.z, P0.w);
    const f2 p1l = mkf2(P1.x, P1.y), p1h = mkf2(P1.z, P1.w);
    const f2 p2l = mkf2(P2.x, P2.y), p2h = mkf2(P2.z, P2.w);
#pragma unroll
    for (int m = 0; m < 2; ++m) {
      const f2 sl = fma2(p0l, cqxs[m], fma2(p1l, cqys[m], fma2(p2l, cqzs[m], cqcs[m])));
      const f2 sh = fma2(p0h, cqxs[m], fma2(p1h, cqys[m], fma2(p2h, cqzs[m], cqcs[m])));
      const f2 el = mkf2(EXP2(sl.x), EXP2(sl.y));
      const f2 eh = mkf2(EXP2(sh.x), EXP2(sh.y));
      ddp[m] = ddp[m] + el + eh;
      d0p[m] = fma2(el, p0l, fma2(eh, p0h, d0p[m]));
      d1p[m] = fma2(el, p1l, fma2(eh, p1h, d1p[m]));
      d2p[m] = fma2(el, p2l, fma2(eh, p2h, d2p[m]));
    }
  }
#pragma unroll
  for (int m = 0; m < 2; ++m) {
    da0[m] = d0p[m].x + d0p[m].y; C8S(da0[m]);
    da1[m] = d1p[m].x + d1p[m].y; C8S(da1[m]);
    da2[m] = d2p[m].x + d2p[m].y; C8S(da2[m]);
    ddn[m] = ddp[m].x + ddp[m].y; C8S(ddn[m]);
  }
  {
    const float myd = sel2(ddn[0], ddn[1], ms);
    const float rdn = 1.f / myd;
    const float u0 = sel2(da0[0], da0[1], ms) * rdn;
    const float u1 = sel2(da1[0], da1[1], ms) * rdn;
    const float u2 = sel2(da2[0], da2[1], ms) * rdn;
    const float v0 = a2w[18] * u0 + a2w[19] * u1 + a2w[20] * u2 + a2b[6];
    const float v1 = a2w[21] * u0 + a2w[22] * u1 + a2w[23] * u2 + a2b[7];
    const float v2 = a2w[24] * u0 + a2w[25] * u1 + a2w[26] * u2 + a2b[8];
    r0 = a2ow[0] * v0 + a2ow[1] * v1 + a2ow[2] * v2 + a2ob[0] + x2d0;
    r1 = a2ow[3] * v0 + a2ow[4] * v1 + a2ow[5] * v2 + a2ob[1] + x2d1;
    r2 = a2ow[6] * v0 + a2ow[7] * v1 + a2ow[8] * v2 + a2ob[2] + x2d2;
  }
  block_stats(contrib ? r0 + r1 + r2 : 0.f,
              contrib ? r0 * r0 + r1 * r1 + r2 * r2 : 0.f, sRed + 48, t, 384.f, mean2, rstd2);
  const float x30 = (r0 - mean2) * rstd2 * dl1w0 + dl1b0;   // dec_ln1 AGAIN
  const float x31 = (r1 - mean2) * rstd2 * dl1w1 + dl1b1;
  const float x32 = (r2 - mean2) * rstd2 * dl1w2 + dl1b2;

  // dec FFN: both rows' x3 as h2 broadcasts (DPP pair-swap + selects)
  unsigned x3x0, x3y0, x3z0, x3x1, x3y1, x3z1;
  {
    const unsigned xx = pk16(x30, x30), xy = pk16(x31, x31), xz = pk16(x32, x32);
    const unsigned oxx = DPPU(xx, 0x11);
    const unsigned oxy = DPPU(xy, 0x11);
    const unsigned oxz = DPPU(xz, 0x11);
    x3x0 = ms ? oxx : xx; x3y0 = ms ? oxy : xy; x3z0 = ms ? oxz : xz;
    x3x1 = ms ? xx : oxx; x3y1 = ms ? xy : oxy; x3z1 = ms ? xz : oxz;
  }
  float e0[2] = {0, 0}, e1[2] = {0, 0}, e2[2] = {0, 0};
#pragma unroll 4
  for (int jj = 0; jj < 32; ++jj) {
    const int pp = 8 * jj + s;
    const uint4 A = sFD[2 * pp];
    const uint4 B = sFD[2 * pp + 1];
    const h2 w1x = uph(A.x), w1y = uph(A.y), w1z = uph(A.z), b1h = uph(A.w);
    const h2 w2x = uph(B.x), w2y = uph(B.y), w2z = uph(B.z);
#pragma unroll
    for (int m = 0; m < 2; ++m) {
      h2 z = w1z * uph(m ? x3z1 : x3z0) + b1h;
      z = w1y * uph(m ? x3y1 : x3y0) + z;
      z = w1x * uph(m ? x3x1 : x3x0) + z;
      z = relu2(z);
      e0[m] = FDOT2(z, w2x, e0[m]);
      e1[m] = FDOT2(z, w2y, e1[m]);
      e2[m] = FDOT2(z, w2z, e2[m]);
    }
  }
#pragma unroll
  for (int m = 0; m < 2; ++m) { C8S(e0[m]); C8S(e1[m]); C8S(e2[m]); }

  const float f0 = sel2(e0[0], e0[1], ms) + db2[0] + x30;
  const float f1 = sel2(e1[0], e1[1], ms) + db2[1] + x31;
  const float f2v = sel2(e2[0], e2[1], ms) + db2[2] + x32;
  block_stats(contrib ? f0 + f1 + f2v : 0.f,
              contrib ? f0 * f0 + f1 * f1 + f2v * f2v : 0.f, sRed + 64, t, 384.f, mean2, rstd2);
  if (s < 2) {
    float* op = out + ((size_t)b * SPRQ + ra) * 3;
    op[0] = (f0 - mean2) * rstd2 * dln3w[lid + 0] + dln3b[lid + 0];
    op[1] = (f1 - mean2) * rstd2 * dln3w[lid + 1] + dln3b[lid + 1];
    op[2] = (f2v - mean2) * rstd2 * dln3w[lid + 2] + dln3b[lid + 2];
  }
}

extern "C" void kernel_launch(void* const* d_in, const int* in_sizes, int n_in,
                              void* d_out, int out_size, void* d_ws, size_t ws_size,
                              hipStream_t stream) {
  (void)in_sizes; (void)n_in; (void)out_size; (void)d_ws; (void)ws_size;

  fused_fwd<<<NB, 512, 0, stream>>>(
      (const float*)d_in[0],  (const float*)d_in[1],
      (const float*)d_in[2],  (const float*)d_in[3],
      (const float*)d_in[4],  (const float*)d_in[5],
      (const float*)d_in[6],  (const float*)d_in[7],
      (const float*)d_in[11],
      (const float*)d_in[12], (const float*)d_in[13],
      (const float*)d_in[14], (const float*)d_in[15],
      (const float*)d_in[16], (const float*)d_in[17],
      (const float*)d_in[18], (const float*)d_in[19],
      (const float*)d_in[20], (const float*)d_in[21],
      (const float*)d_in[22], (const float*)d_in[23],
      (const float*)d_in[27],
      (const float*)d_in[28], (const float*)d_in[29],
      (const float*)d_in[8],  (const float*)d_in[9],  (const float*)d_in[10],
      (const float*)d_in[24], (const float*)d_in[25], (const float*)d_in[26],
      (float*)d_out);
}

// Round 14
// 167.451 us; speedup vs baseline: 1.2160x; 1.0427x over previous
//
#include <hip/hip_runtime.h>

#define NB   1024
#define SINQ 256
#define SPRQ 128
#define HIDQ 512

// pos_enc: emb[:, :3] = sin(pos * inv_freq[c]); inv_freq[c] = 10000^(-2c/256)
#define PEF1  0.93057207f
#define PEF2  0.86596438f
#define LOG2E 1.44269504089f
// q pre-scale: 1/sqrt(3) * log2(e)
#define QS    0.83298066476f

typedef _Float16 h2 __attribute__((ext_vector_type(2)));
typedef float    f2 __attribute__((ext_vector_type(2)));

#if defined(__has_builtin) && __has_builtin(__builtin_amdgcn_exp2f)
#define EXP2(x) __builtin_amdgcn_exp2f(x)
#else
#define EXP2(x) exp2f(x)
#endif

#if defined(__has_builtin) && __has_builtin(__builtin_amdgcn_fdot2)
#define FDOT2(a, b, c) __builtin_amdgcn_fdot2((a), (b), (c), false)
#else
__device__ __forceinline__ float fdot2_sw(h2 a, h2 b, float c) {
  return fmaf((float)a.x, (float)b.x, fmaf((float)a.y, (float)b.y, c));
}
#define FDOT2(a, b, c) fdot2_sw((a), (b), (c))
#endif

__device__ __forceinline__ unsigned pk16(float a, float b) {
  h2 v; v.x = (_Float16)a; v.y = (_Float16)b;
  return __builtin_bit_cast(unsigned, v);
}
__device__ __forceinline__ h2 uph(unsigned u) { return __builtin_bit_cast(h2, u); }

__device__ __forceinline__ h2 relu2(h2 z) {
#if defined(__has_builtin) && __has_builtin(__builtin_elementwise_max)
  h2 zz; zz.x = (_Float16)0.f; zz.y = (_Float16)0.f;
  return __builtin_elementwise_max(z, zz);
#else
  z.x = z.x > (_Float16)0.f ? z.x : (_Float16)0.f;
  z.y = z.y > (_Float16)0.f ? z.y : (_Float16)0.f;
  return z;
#endif
}

__device__ __forceinline__ f2 mkf2(float a, float b) { f2 r; r.x = a; r.y = b; return r; }
__device__ __forceinline__ f2 spl(float a) { f2 r; r.x = a; r.y = a; return r; }
#if defined(__has_builtin) && __has_builtin(__builtin_elementwise_fma)
__device__ __forceinline__ f2 fma2(f2 a, f2 b, f2 c) {
  return __builtin_elementwise_fma(a, b, c);   // v_pk_fma_f32
}
#else
__device__ __forceinline__ f2 fma2(f2 a, f2 b, f2 c) {
  f2 r; r.x = fmaf(a.x, b.x, c.x); r.y = fmaf(a.y, b.y, c.y); return r;
}
#endif

// ---- DPP quad_perm cross-lane --------------------------------------------
// PROVEN-SAFE on gfx950 (R6/R7/R9 passing): quad_perm 0xB1/0x4E (xor1/xor2),
// quad-broadcast 0x00/0x55/0xAA/0xFF, pair-swap 0x11.
// OFF-LIMITS: ROW_MIRROR/ROW_HALF_MIRROR (0x140/0x141) — removed on CDNA
// (caused the R1 absmax-8.78 failure). Cross-quad strides stay __shfl_xor.
//
// CONVERGENCE LEDGER (R13 final): 71.5 -> 62.4 (quad-T packed-f32 attn, R4)
// -> 60.1 us (DPP + query-dedup + barrier cut, R6-R9). Refuted levers:
//  - dot2/cvt_pkrtz V-accum (R10/R11): issued MORE VALU than pk_fma f32.
//  - LN-weight prefetch (R8): +12 live VGPR -> spill cliff (WRITE 1536->4608).
//  - 8-way/512-thr split @(512,8) (R12): VGPR cap 64 -> 113 MB scratch.
//  - 8-way/512-thr split @(512,6) (R13): no spill but bank conflicts x10
//    (417K->4.78M) + dup work + C8S shfl stage = +25% issued -> 71 us.
// The 4-way/256-thr decomposition is communication-optimal for this op.
#define DPPF(x, ctrl) __builtin_bit_cast(float, __builtin_amdgcn_update_dpp( \
    0, __builtin_bit_cast(int, (x)), (ctrl), 0xF, 0xF, true))
#define DPPU(x, ctrl) ((unsigned)__builtin_amdgcn_update_dpp( \
    0, (int)(x), (ctrl), 0xF, 0xF, true))

// xor-combine over the 4 slot lanes of a quad (DPP quad_perm).
#define C4S(v)  { (v) += DPPF((v), 0xB1); (v) += DPPF((v), 0x4E); }

// register-only selects (v_cndmask chains) -- NEVER index private arrays
// with a runtime value: that demotes them to scratch (HBM!).
__device__ __forceinline__ float sel4(float a, float b, float c, float d, int s) {
  float r = a;
  r = (s == 1) ? b : r;
  r = (s == 2) ? c : r;
  r = (s == 3) ? d : r;
  return r;
}
__device__ __forceinline__ float sel2(float a, float b, int s) {
  return s ? b : a;
}

// Block-wide (256 thr) mean/rstd over nelem values. One barrier per call:
// each call gets its own sRed slot (rotation removes the WAR pre-barrier).
// Strides 1,2 via quad_perm DPP; 4..32 via shfl (NO mirror DPP on CDNA!).
__device__ __forceinline__ void block_stats(float s1, float s2, float* slot,
                                            int tid, float nelem,
                                            float& mean, float& rstd) {
  s1 += DPPF(s1, 0xB1); s2 += DPPF(s2, 0xB1);
  s1 += DPPF(s1, 0x4E); s2 += DPPF(s2, 0x4E);
#pragma unroll
  for (int off = 32; off >= 4; off >>= 1) {
    s1 += __shfl_xor(s1, off, 64);
    s2 += __shfl_xor(s2, off, 64);
  }
  if ((tid & 63) == 0) {
    slot[((tid >> 6) << 1) + 0] = s1;
    slot[((tid >> 6) << 1) + 1] = s2;
  }
  __syncthreads();
  float t1 = slot[0] + slot[2] + slot[4] + slot[6];
  float t2 = slot[1] + slot[3] + slot[5] + slot[7];
  mean = t1 / nelem;
  rstd = rsqrtf(t2 / nelem - mean * mean + 1e-5f);
}

// One 256-thr block per batch element. pack_tabs folded in (R5). 4-way
// slot-split (s = t&3) over key-QUADS via transposed LDS (R4). Quad-local
// shuffles via DPP (R6). Queries built once per row (R7). Barrier cut +
// seed precompute (R9). This is the converged configuration.
__global__ __launch_bounds__(256, 4) void fused_fwd(
    const float* __restrict__ X, const float* __restrict__ T,
    const float* __restrict__ einw, const float* __restrict__ einb,
    const float* __restrict__ eow,  const float* __restrict__ eob,
    const float* __restrict__ eln1w, const float* __restrict__ eln1b,
    const float* __restrict__ eb2,
    const float* __restrict__ eln2w, const float* __restrict__ eln2b,
    const float* __restrict__ a1w, const float* __restrict__ a1b,
    const float* __restrict__ a1ow, const float* __restrict__ a1ob,
    const float* __restrict__ dln1w, const float* __restrict__ dln1b,
    const float* __restrict__ a2w, const float* __restrict__ a2b,
    const float* __restrict__ a2ow, const float* __restrict__ a2ob,
    const float* __restrict__ db2,
    const float* __restrict__ dln3w, const float* __restrict__ dln3b,
    const float* __restrict__ ew1, const float* __restrict__ eb1,
    const float* __restrict__ ew2,
    const float* __restrict__ dw1, const float* __restrict__ db1,
    const float* __restrict__ dw2,
    float* __restrict__ out)
{
  __shared__ uint4  sFE[2 * 256];                       // 8 KB enc FFN
  __shared__ uint4  sFD[2 * 256];                       // 8 KB dec FFN
  __shared__ float4 sEP[SINQ];                          // 4 KB p_X rows
  __shared__ float4 sDP[SPRQ];                          // 2 KB p_T rows
  __shared__ __align__(16) float sEPq[(SINQ / 4) * 12]; // 3 KB p_X quad-T
  __shared__ __align__(16) float sDPq[(SPRQ / 4) * 12]; // 1.5 KB p_T quad-T
  __shared__ __align__(16) float sCEq[(SINQ / 4) * 12]; // 3 KB enc_out quad-T
  __shared__ float  sRed[5 * 8];                        // per-call slots

  const int b = blockIdx.x;
  const int t = threadIdx.x;
  const int s = t & 3;             // slot
  const int g = t >> 2;            // enc row-group (0..63)

  // ---- pack FFN pair-records from global (float2-vectorized, R7).
  {
    const float2 e10 = *(const float2*)&ew1[6 * t];
    const float2 e11 = *(const float2*)&ew1[6 * t + 2];
    const float2 e12 = *(const float2*)&ew1[6 * t + 4];
    const float2 eb  = *(const float2*)&eb1[2 * t];
    sFE[2 * t] = make_uint4(pk16(e10.x, e11.y), pk16(e10.y, e12.x),
                            pk16(e11.x, e12.y), pk16(eb.x, eb.y));
    const float2 w20 = *(const float2*)&ew2[2 * t];
    const float2 w21 = *(const float2*)&ew2[HIDQ + 2 * t];
    const float2 w22 = *(const float2*)&ew2[2 * HIDQ + 2 * t];
    sFE[2 * t + 1] = make_uint4(pk16(w20.x, w20.y), pk16(w21.x, w21.y),
                                pk16(w22.x, w22.y), 0u);
    const float2 d10 = *(const float2*)&dw1[6 * t];
    const float2 d11 = *(const float2*)&dw1[6 * t + 2];
    const float2 d12 = *(const float2*)&dw1[6 * t + 4];
    const float2 dbv = *(const float2*)&db1[2 * t];
    sFD[2 * t] = make_uint4(pk16(d10.x, d11.y), pk16(d10.y, d12.x),
                            pk16(d11.x, d12.y), pk16(dbv.x, dbv.y));
    const float2 v20 = *(const float2*)&dw2[2 * t];
    const float2 v21 = *(const float2*)&dw2[HIDQ + 2 * t];
    const float2 v22 = *(const float2*)&dw2[2 * HIDQ + 2 * t];
    sFD[2 * t + 1] = make_uint4(pk16(v20.x, v20.y), pk16(v21.x, v21.y),
                                pk16(v22.x, v22.y), 0u);
  }
  // ---- stage p-rows (row-major AND quad-transposed); own-row pos enc sins
  {
    const float p = (float)t;
    const float pe0 = __sinf(p), pe1 = __sinf(p * PEF1), pe2 = __sinf(p * PEF2);
    const float* xr = X + (size_t)b * SINQ * 3 + 3 * t;
    const float p0 = xr[0] + pe0, p1 = xr[1] + pe1, p2 = xr[2] + pe2;
    sEP[t] = make_float4(p0, p1, p2, 1.f);
    const int q = t >> 2, sl = t & 3;
    sEPq[(q * 3 + 0) * 4 + sl] = p0;
    sEPq[(q * 3 + 1) * 4 + sl] = p1;
    sEPq[(q * 3 + 2) * 4 + sl] = p2;
    if (t < SPRQ) {
      const float* tr = T + (size_t)b * SPRQ * 3 + 3 * t;
      const float d0 = tr[0] + pe0, d1 = tr[1] + pe1, d2 = tr[2] + pe2;
      sDP[t] = make_float4(d0, d1, d2, 1.f);
      sDPq[(q * 3 + 0) * 4 + sl] = d0;
      sDPq[(q * 3 + 1) * 4 + sl] = d1;
      sDPq[(q * 3 + 2) * 4 + sl] = d2;
    }
  }
  __syncthreads();

  const f2 z2 = mkf2(0.f, 0.f);
  float r0, r1, r2;
  float mean, rstd;

  // ================= ENCODER =================
  const int rho = g + 64 * s;
  float pr0, pr1, pr2;
  { const float4 prw = sEP[rho]; pr0 = prw.x; pr1 = prw.y; pr2 = prw.z; }

  // build ONLY own row's query, then quad-broadcast (R7)
  f2 qaO, qbO;
  {
    const float q0 = (einw[0] * pr0 + einw[1] * pr1 + einw[2] * pr2 + einb[0]) * QS;
    const float q1 = (einw[3] * pr0 + einw[4] * pr1 + einw[5] * pr2 + einb[1]) * QS;
    const float q2 = (einw[6] * pr0 + einw[7] * pr1 + einw[8] * pr2 + einb[2]) * QS;
    qaO = mkf2(q0 * einw[9]  + q1 * einw[12] + q2 * einw[15],
               q0 * einw[10] + q1 * einw[13] + q2 * einw[16]);
    qbO = mkf2(q0 * einw[11] + q1 * einw[14] + q2 * einw[17],
               q0 * einb[3]  + q1 * einb[4]  + q2 * einb[5]);
  }
  f2 qxs[4], qys[4], qzs[4], qcs[4];
  qxs[0] = spl(DPPF(qaO.x, 0x00)); qxs[1] = spl(DPPF(qaO.x, 0x55));
  qxs[2] = spl(DPPF(qaO.x, 0xAA)); qxs[3] = spl(DPPF(qaO.x, 0xFF));
  qys[0] = spl(DPPF(qaO.y, 0x00)); qys[1] = spl(DPPF(qaO.y, 0x55));
  qys[2] = spl(DPPF(qaO.y, 0xAA)); qys[3] = spl(DPPF(qaO.y, 0xFF));
  qzs[0] = spl(DPPF(qbO.x, 0x00)); qzs[1] = spl(DPPF(qbO.x, 0x55));
  qzs[2] = spl(DPPF(qbO.x, 0xAA)); qzs[3] = spl(DPPF(qbO.x, 0xFF));
  qcs[0] = spl(DPPF(qbO.y, 0x00)); qcs[1] = spl(DPPF(qbO.y, 0x55));
  qcs[2] = spl(DPPF(qbO.y, 0xAA)); qcs[3] = spl(DPPF(qbO.y, 0xFF));

  // attention: slot s handles key-quads qid = 4*u+s (4 keys each)
  f2 a0p[4], a1p[4], a2p[4], dnp[4];
#pragma unroll
  for (int m = 0; m < 4; ++m) { a0p[m] = z2; a1p[m] = z2; a2p[m] = z2; dnp[m] = z2; }
#pragma unroll 2
  for (int u = 0; u < 16; ++u) {
    const int qid = 4 * u + s;
    const float4 P0 = *(const float4*)&sEPq[(qid * 3 + 0) * 4];
    const float4 P1 = *(const float4*)&sEPq[(qid * 3 + 1) * 4];
    const float4 P2 = *(const float4*)&sEPq[(qid * 3 + 2) * 4];
    const f2 p0l = mkf2(P0.x, P0.y), p0h = mkf2(P0.z, P0.w);
    const f2 p1l = mkf2(P1.x, P1.y), p1h = mkf2(P1.z, P1.w);
    const f2 p2l = mkf2(P2.x, P2.y), p2h = mkf2(P2.z, P2.w);
#pragma unroll
    for (int m = 0; m < 4; ++m) {
      const f2 sl = fma2(p0l, qxs[m], fma2(p1l, qys[m], fma2(p2l, qzs[m], qcs[m])));
      const f2 sh = fma2(p0h, qxs[m], fma2(p1h, qys[m], fma2(p2h, qzs[m], qcs[m])));
      const f2 el = mkf2(EXP2(sl.x), EXP2(sl.y));
      const f2 eh = mkf2(EXP2(sh.x), EXP2(sh.y));
      dnp[m] = dnp[m] + el + eh;
      a0p[m] = fma2(el, p0l, fma2(eh, p0h, a0p[m]));
      a1p[m] = fma2(el, p1l, fma2(eh, p1h, a1p[m]));
      a2p[m] = fma2(el, p2l, fma2(eh, p2h, a2p[m]));
    }
  }
  float aa0[4], aa1[4], aa2[4], adn[4];
#pragma unroll
  for (int m = 0; m < 4; ++m) {
    aa0[m] = a0p[m].x + a0p[m].y; C4S(aa0[m]);
    aa1[m] = a1p[m].x + a1p[m].y; C4S(aa1[m]);
    aa2[m] = a2p[m].x + a2p[m].y; C4S(aa2[m]);
    adn[m] = dnp[m].x + dnp[m].y; C4S(adn[m]);
  }

  {
    const float myd  = sel4(adn[0], adn[1], adn[2], adn[3], s);
    const float mya0 = sel4(aa0[0], aa0[1], aa0[2], aa0[3], s);
    const float mya1 = sel4(aa1[0], aa1[1], aa1[2], aa1[3], s);
    const float mya2 = sel4(aa2[0], aa2[1], aa2[2], aa2[3], s);
    const float rdn = 1.f / myd;
    const float u0 = mya0 * rdn, u1 = mya1 * rdn, u2 = mya2 * rdn;
    const float v0 = einw[18] * u0 + einw[19] * u1 + einw[20] * u2 + einb[6];
    const float v1 = einw[21] * u0 + einw[22] * u1 + einw[23] * u2 + einb[7];
    const float v2 = einw[24] * u0 + einw[25] * u1 + einw[26] * u2 + einb[8];
    r0 = eow[0] * v0 + eow[1] * v1 + eow[2] * v2 + eob[0] + pr0;
    r1 = eow[3] * v0 + eow[4] * v1 + eow[5] * v2 + eob[1] + pr1;
    r2 = eow[6] * v0 + eow[7] * v1 + eow[8] * v2 + eob[2] + pr2;
  }
  block_stats(r0 + r1 + r2, r0 * r0 + r1 * r1 + r2 * r2, sRed + 0, t, 768.f, mean, rstd);
  const int lie = rho * 3;
  const float x20 = (r0 - mean) * rstd * eln1w[lie + 0] + eln1b[lie + 0];
  const float x21 = (r1 - mean) * rstd * eln1w[lie + 1] + eln1b[lie + 1];
  const float x22 = (r2 - mean) * rstd * eln1w[lie + 2] + eln1b[lie + 2];

  // FFN: slot s handles pairs pp = 4*jj+s over 4 quad-gathered rows (DPP bcast)
  unsigned xxm[4], xym[4], xzm[4];
  {
    const unsigned xx = pk16(x20, x20), xy = pk16(x21, x21), xz = pk16(x22, x22);
    xxm[0] = DPPU(xx, 0x00); xym[0] = DPPU(xy, 0x00); xzm[0] = DPPU(xz, 0x00);
    xxm[1] = DPPU(xx, 0x55); xym[1] = DPPU(xy, 0x55); xzm[1] = DPPU(xz, 0x55);
    xxm[2] = DPPU(xx, 0xAA); xym[2] = DPPU(xy, 0xAA); xzm[2] = DPPU(xz, 0xAA);
    xxm[3] = DPPU(xx, 0xFF); xym[3] = DPPU(xy, 0xFF); xzm[3] = DPPU(xz, 0xFF);
  }
  float c0[4] = {0, 0, 0, 0}, c1[4] = {0, 0, 0, 0}, c2[4] = {0, 0, 0, 0};
#pragma unroll 4
  for (int jj = 0; jj < 64; ++jj) {
    const int pp = 4 * jj + s;
    const uint4 A = sFE[2 * pp];
    const uint4 B = sFE[2 * pp + 1];
    const h2 w1x = uph(A.x), w1y = uph(A.y), w1z = uph(A.z), b1h = uph(A.w);
    const h2 w2x = uph(B.x), w2y = uph(B.y), w2z = uph(B.z);
#pragma unroll
    for (int m = 0; m < 4; ++m) {
      h2 z = w1z * uph(xzm[m]) + b1h;
      z = w1y * uph(xym[m]) + z;
      z = w1x * uph(xxm[m]) + z;
      z = relu2(z);
      c0[m] = FDOT2(z, w2x, c0[m]);
      c1[m] = FDOT2(z, w2y, c1[m]);
      c2[m] = FDOT2(z, w2z, c2[m]);
    }
  }
#pragma unroll
  for (int m = 0; m < 4; ++m) { C4S(c0[m]); C4S(c1[m]); C4S(c2[m]); }

  const float h0 = sel4(c0[0], c0[1], c0[2], c0[3], s) + eb2[0] + x20;
  const float h1 = sel4(c1[0], c1[1], c1[2], c1[3], s) + eb2[1] + x21;
  const float h2v = sel4(c2[0], c2[1], c2[2], c2[3], s) + eb2[2] + x22;
  block_stats(h0 + h1 + h2v, h0 * h0 + h1 * h1 + h2v * h2v, sRed + 8, t, 768.f, mean, rstd);
  {
    const float e0 = (h0 - mean) * rstd * eln2w[lie + 0] + eln2b[lie + 0];
    const float e1 = (h1 - mean) * rstd * eln2w[lie + 1] + eln2b[lie + 1];
    const float e2 = (h2v - mean) * rstd * eln2w[lie + 2] + eln2b[lie + 2];
    const int q = rho >> 2, sl = rho & 3;
    sCEq[(q * 3 + 0) * 4 + sl] = e0;
    sCEq[(q * 3 + 1) * 4 + sl] = e1;
    sCEq[(q * 3 + 2) * 4 + sl] = e2;
  }
  // NOTE (R9): no __syncthreads here — the dec-self block_stats barrier
  // below orders all sCEq writes before any cross-attn read.

  // ================= DECODER =================
  const int ms = s & 1;            // assigned row: ra = g + 64*ms
  const int ra = g + 64 * ms;

  float pt0, pt1, pt2;
  { const float4 prw = sDP[ra]; pt0 = prw.x; pt1 = prw.y; pt2 = prw.z; }

  // own row's self-attn query; other row via pair-swap 0x11 (R7)
  f2 dqaO, dqbO;
  {
    const float q0 = (a1w[0] * pt0 + a1w[1] * pt1 + a1w[2] * pt2 + a1b[0]) * QS;
    const float q1 = (a1w[3] * pt0 + a1w[4] * pt1 + a1w[5] * pt2 + a1b[1]) * QS;
    const float q2 = (a1w[6] * pt0 + a1w[7] * pt1 + a1w[8] * pt2 + a1b[2]) * QS;
    dqaO = mkf2(q0 * a1w[9]  + q1 * a1w[12] + q2 * a1w[15],
                q0 * a1w[10] + q1 * a1w[13] + q2 * a1w[16]);
    dqbO = mkf2(q0 * a1w[11] + q1 * a1w[14] + q2 * a1w[17],
                q0 * a1b[3]  + q1 * a1b[4]  + q2 * a1b[5]);
  }
  f2 dqxs[2], dqys[2], dqzs[2];
  float ds0[2], dsE[2];            // seed and seed+LOG2E precomputed
  {
    const float oax = DPPF(dqaO.x, 0x11), oay = DPPF(dqaO.y, 0x11);
    const float obx = DPPF(dqbO.x, 0x11), oby = DPPF(dqbO.y, 0x11);
    dqxs[0] = spl(ms ? oax : dqaO.x); dqxs[1] = spl(ms ? dqaO.x : oax);
    dqys[0] = spl(ms ? oay : dqaO.y); dqys[1] = spl(ms ? dqaO.y : oay);
    dqzs[0] = spl(ms ? obx : dqbO.x); dqzs[1] = spl(ms ? dqbO.x : obx);
    ds0[0] = ms ? oby : dqbO.y;       ds0[1] = ms ? dqbO.y : oby;
    dsE[0] = ds0[0] + LOG2E;          dsE[1] = ds0[1] + LOG2E;
  }

  // self-attn (additive tril(ones) mask -> seed = ds0/dsE by j<=row)
  f2 d0p[2], d1p[2], d2p[2], ddp[2];
#pragma unroll
  for (int m = 0; m < 2; ++m) { d0p[m] = z2; d1p[m] = z2; d2p[m] = z2; ddp[m] = z2; }
#pragma unroll 2
  for (int u = 0; u < 8; ++u) {
    const int qid = 4 * u + s;
    const int j0 = 4 * qid;
    const float4 P0 = *(const float4*)&sDPq[(qid * 3 + 0) * 4];
    const float4 P1 = *(const float4*)&sDPq[(qid * 3 + 1) * 4];
    const float4 P2 = *(const float4*)&sDPq[(qid * 3 + 2) * 4];
    const f2 p0l = mkf2(P0.x, P0.y), p0h = mkf2(P0.z, P0.w);
    const f2 p1l = mkf2(P1.x, P1.y), p1h = mkf2(P1.z, P1.w);
    const f2 p2l = mkf2(P2.x, P2.y), p2h = mkf2(P2.z, P2.w);
#pragma unroll
    for (int m = 0; m < 2; ++m) {
      const int row = g + 64 * m;
      const f2 seedl = mkf2(j0 + 0 <= row ? dsE[m] : ds0[m],
                            j0 + 1 <= row ? dsE[m] : ds0[m]);
      const f2 seedh = mkf2(j0 + 2 <= row ? dsE[m] : ds0[m],
                            j0 + 3 <= row ? dsE[m] : ds0[m]);
      const f2 sl = fma2(p0l, dqxs[m], fma2(p1l, dqys[m], fma2(p2l, dqzs[m], seedl)));
      const f2 sh = fma2(p0h, dqxs[m], fma2(p1h, dqys[m], fma2(p2h, dqzs[m], seedh)));
      const f2 el = mkf2(EXP2(sl.x), EXP2(sl.y));
      const f2 eh = mkf2(EXP2(sh.x), EXP2(sh.y));
      ddp[m] = ddp[m] + el + eh;
      d0p[m] = fma2(el, p0l, fma2(eh, p0h, d0p[m]));
      d1p[m] = fma2(el, p1l, fma2(eh, p1h, d1p[m]));
      d2p[m] = fma2(el, p2l, fma2(eh, p2h, d2p[m]));
    }
  }
  float da0[2], da1[2], da2[2], ddn[2];
#pragma unroll
  for (int m = 0; m < 2; ++m) {
    da0[m] = d0p[m].x + d0p[m].y; C4S(da0[m]);
    da1[m] = d1p[m].x + d1p[m].y; C4S(da1[m]);
    da2[m] = d2p[m].x + d2p[m].y; C4S(da2[m]);
    ddn[m] = ddp[m].x + ddp[m].y; C4S(ddn[m]);
  }
  {
    const float myd = sel2(ddn[0], ddn[1], ms);
    const float rdn = 1.f / myd;
    const float u0 = sel2(da0[0], da0[1], ms) * rdn;
    const float u1 = sel2(da1[0], da1[1], ms) * rdn;
    const float u2 = sel2(da2[0], da2[1], ms) * rdn;
    const float v0 = a1w[18] * u0 + a1w[19] * u1 + a1w[20] * u2 + a1b[6];
    const float v1 = a1w[21] * u0 + a1w[22] * u1 + a1w[23] * u2 + a1b[7];
    const float v2 = a1w[24] * u0 + a1w[25] * u1 + a1w[26] * u2 + a1b[8];
    r0 = a1ow[0] * v0 + a1ow[1] * v1 + a1ow[2] * v2 + a1ob[0] + pt0;
    r1 = a1ow[3] * v0 + a1ow[4] * v1 + a1ow[5] * v2 + a1ob[1] + pt1;
    r2 = a1ow[6] * v0 + a1ow[7] * v1 + a1ow[8] * v2 + a1ob[2] + pt2;
  }
  const int contrib = (s < 2) ? 1 : 0;
  float mean2, rstd2;
  block_stats(contrib ? r0 + r1 + r2 : 0.f,
              contrib ? r0 * r0 + r1 * r1 + r2 * r2 : 0.f, sRed + 16, t, 384.f, mean2, rstd2);
  const int lid = ra * 3;
  const float dl1w0 = dln1w[lid + 0], dl1w1 = dln1w[lid + 1], dl1w2 = dln1w[lid + 2];
  const float dl1b0 = dln1b[lid + 0], dl1b1 = dln1b[lid + 1], dl1b2 = dln1b[lid + 2];
  const float x2d0 = (r0 - mean2) * rstd2 * dl1w0 + dl1b0;
  const float x2d1 = (r1 - mean2) * rstd2 * dl1w1 + dl1b1;
  const float x2d2 = (r2 - mean2) * rstd2 * dl1w2 + dl1b2;

  // cross-attn query built from OWN row's x2d; other row via 0x11 swap (R7)
  f2 cqaO, cqbO;
  {
    const float q0 = (a2w[0] * x2d0 + a2w[1] * x2d1 + a2w[2] * x2d2 + a2b[0]) * QS;
    const float q1 = (a2w[3] * x2d0 + a2w[4] * x2d1 + a2w[5] * x2d2 + a2b[1]) * QS;
    const float q2 = (a2w[6] * x2d0 + a2w[7] * x2d1 + a2w[8] * x2d2 + a2b[2]) * QS;
    cqaO = mkf2(q0 * a2w[9]  + q1 * a2w[12] + q2 * a2w[15],
                q0 * a2w[10] + q1 * a2w[13] + q2 * a2w[16]);
    cqbO = mkf2(q0 * a2w[11] + q1 * a2w[14] + q2 * a2w[17],
                q0 * a2b[3]  + q1 * a2b[4]  + q2 * a2b[5]);
  }
  f2 cqxs[2], cqys[2], cqzs[2], cqcs[2];
  {
    const float oax = DPPF(cqaO.x, 0x11), oay = DPPF(cqaO.y, 0x11);
    const float obx = DPPF(cqbO.x, 0x11), oby = DPPF(cqbO.y, 0x11);
    cqxs[0] = spl(ms ? oax : cqaO.x); cqxs[1] = spl(ms ? cqaO.x : oax);
    cqys[0] = spl(ms ? oay : cqaO.y); cqys[1] = spl(ms ? cqaO.y : oay);
    cqzs[0] = spl(ms ? obx : cqbO.x); cqzs[1] = spl(ms ? cqbO.x : obx);
    cqcs[0] = spl(ms ? oby : cqbO.y); cqcs[1] = spl(ms ? cqbO.y : oby);
  }
#pragma unroll
  for (int m = 0; m < 2; ++m) { d0p[m] = z2; d1p[m] = z2; d2p[m] = z2; ddp[m] = z2; }
#pragma unroll 2
  for (int u = 0; u < 16; ++u) {
    const int qid = 4 * u + s;
    const float4 P0 = *(const float4*)&sCEq[(qid * 3 + 0) * 4];
    const float4 P1 = *(const float4*)&sCEq[(qid * 3 + 1) * 4];
    const float4 P2 = *(const float4*)&sCEq[(qid * 3 + 2) * 4];
    const f2 p0l = mkf2(P0.x, P0.y), p0h = mkf2(P0.z, P0.w);
    const f2 p1l = mkf2(P1.x, P1.y), p1h = mkf2(P1.z, P1.w);
    const f2 p2l = mkf2(P2.x, P2.y), p2h = mkf2(P2.z, P2.w);
#pragma unroll
    for (int m = 0; m < 2; ++m) {
      const f2 sl = fma2(p0l, cqxs[m], fma2(p1l, cqys[m], fma2(p2l, cqzs[m], cqcs[m])));
      const f2 sh = fma2(p0h, cqxs[m], fma2(p1h, cqys[m], fma2(p2h, cqzs[m], cqcs[m])));
      const f2 el = mkf2(EXP2(sl.x), EXP2(sl.y));
      const f2 eh = mkf2(EXP2(sh.x), EXP2(sh.y));
      ddp[m] = ddp[m] + el + eh;
      d0p[m] = fma2(el, p0l, fma2(eh, p0h, d0p[m]));
      d1p[m] = fma2(el, p1l, fma2(eh, p1h, d1p[m]));
      d2p[m] = fma2(el, p2l, fma2(eh, p2h, d2p[m]));
    }
  }
#pragma unroll
  for (int m = 0; m < 2; ++m) {
    da0[m] = d0p[m].x + d0p[m].y; C4S(da0[m]);
    da1[m] = d1p[m].x + d1p[m].y; C4S(da1[m]);
    da2[m] = d2p[m].x + d2p[m].y; C4S(da2[m]);
    ddn[m] = ddp[m].x + ddp[m].y; C4S(ddn[m]);
  }
  {
    const float myd = sel2(ddn[0], ddn[1], ms);
    const float rdn = 1.f / myd;
    const float u0 = sel2(da0[0], da0[1], ms) * rdn;
    const float u1 = sel2(da1[0], da1[1], ms) * rdn;
    const float u2 = sel2(da2[0], da2[1], ms) * rdn;
    const float v0 = a2w[18] * u0 + a2w[19] * u1 + a2w[20] * u2 + a2b[6];
    const float v1 = a2w[21] * u0 + a2w[22] * u1 + a2w[23] * u2 + a2b[7];
    const float v2 = a2w[24] * u0 + a2w[25] * u1 + a2w[26] * u2 + a2b[8];
    r0 = a2ow[0] * v0 + a2ow[1] * v1 + a2ow[2] * v2 + a2ob[0] + x2d0;
    r1 = a2ow[3] * v0 + a2ow[4] * v1 + a2ow[5] * v2 + a2ob[1] + x2d1;
    r2 = a2ow[6] * v0 + a2ow[7] * v1 + a2ow[8] * v2 + a2ob[2] + x2d2;
  }
  block_stats(contrib ? r0 + r1 + r2 : 0.f,
              contrib ? r0 * r0 + r1 * r1 + r2 * r2 : 0.f, sRed + 24, t, 384.f, mean2, rstd2);
  const float x30 = (r0 - mean2) * rstd2 * dl1w0 + dl1b0;   // dec_ln1 AGAIN
  const float x31 = (r1 - mean2) * rstd2 * dl1w1 + dl1b1;
  const float x32 = (r2 - mean2) * rstd2 * dl1w2 + dl1b2;

  // dec FFN: both rows' x3 as h2 broadcasts (DPP pair-swap + selects)
  unsigned x3x0, x3y0, x3z0, x3x1, x3y1, x3z1;
  {
    const unsigned xx = pk16(x30, x30), xy = pk16(x31, x31), xz = pk16(x32, x32);
    const unsigned oxx = DPPU(xx, 0x11);
    const unsigned oxy = DPPU(xy, 0x11);
    const unsigned oxz = DPPU(xz, 0x11);
    x3x0 = ms ? oxx : xx; x3y0 = ms ? oxy : xy; x3z0 = ms ? oxz : xz;
    x3x1 = ms ? xx : oxx; x3y1 = ms ? xy : oxy; x3z1 = ms ? xz : oxz;
  }
  float e0[2] = {0, 0}, e1[2] = {0, 0}, e2[2] = {0, 0};
#pragma unroll 4
  for (int jj = 0; jj < 64; ++jj) {
    const int pp = 4 * jj + s;
    const uint4 A = sFD[2 * pp];
    const uint4 B = sFD[2 * pp + 1];
    const h2 w1x = uph(A.x), w1y = uph(A.y), w1z = uph(A.z), b1h = uph(A.w);
    const h2 w2x = uph(B.x), w2y = uph(B.y), w2z = uph(B.z);
#pragma unroll
    for (int m = 0; m < 2; ++m) {
      h2 z = w1z * uph(m ? x3z1 : x3z0) + b1h;
      z = w1y * uph(m ? x3y1 : x3y0) + z;
      z = w1x * uph(m ? x3x1 : x3x0) + z;
      z = relu2(z);
      e0[m] = FDOT2(z, w2x, e0[m]);
      e1[m] = FDOT2(z, w2y, e1[m]);
      e2[m] = FDOT2(z, w2z, e2[m]);
    }
  }
#pragma unroll
  for (int m = 0; m < 2; ++m) { C4S(e0[m]); C4S(e1[m]); C4S(e2[m]); }

  const float f0 = sel2(e0[0], e0[1], ms) + db2[0] + x30;
  const float f1 = sel2(e1[0], e1[1], ms) + db2[1] + x31;
  const float f2v = sel2(e2[0], e2[1], ms) + db2[2] + x32;
  block_stats(contrib ? f0 + f1 + f2v : 0.f,
              contrib ? f0 * f0 + f1 * f1 + f2v * f2v : 0.f, sRed + 32, t, 384.f, mean2, rstd2);
  if (s < 2) {
    float* op = out + ((size_t)b * SPRQ + ra) * 3;
    op[0] = (f0 - mean2) * rstd2 * dln3w[lid + 0] + dln3b[lid + 0];
    op[1] = (f1 - mean2) * rstd2 * dln3w[lid + 1] + dln3b[lid + 1];
    op[2] = (f2v - mean2) * rstd2 * dln3w[lid + 2] + dln3b[lid + 2];
  }
}

extern "C" void kernel_launch(void* const* d_in, const int* in_sizes, int n_in,
                              void* d_out, int out_size, void* d_ws, size_t ws_size,
                              hipStream_t stream) {
  (void)in_sizes; (void)n_in; (void)out_size; (void)d_ws; (void)ws_size;

  fused_fwd<<<NB, 256, 0, stream>>>(
      (const float*)d_in[0],  (const float*)d_in[1],
      (const float*)d_in[2],  (const float*)d_in[3],
      (const float*)d_in[4],  (const float*)d_in[5],
      (const float*)d_in[6],  (const float*)d_in[7],
      (const float*)d_in[11],
      (const float*)d_in[12], (const float*)d_in[13],
      (const float*)d_in[14], (const float*)d_in[15],
      (const float*)d_in[16], (const float*)d_in[17],
      (const float*)d_in[18], (const float*)d_in[19],
      (const float*)d_in[20], (const float*)d_in[21],
      (const float*)d_in[22], (const float*)d_in[23],
      (const float*)d_in[27],
      (const float*)d_in[28], (const float*)d_in[29],
      (const float*)d_in[8],  (const float*)d_in[9],  (const float*)d_in[10],
      (const float*)d_in[24], (const float*)d_in[25], (const float*)d_in[26],
      (float*)d_out);
}